// Round 1
// baseline (147.890 us; speedup 1.0000x reference)
//
#include <hip/hip_runtime.h>
#include <hip/hip_bf16.h>

#define BATCH 8
#define SEQ   2048
#define DMODEL 1024
#define HD    64

typedef __attribute__((ext_vector_type(8))) short bf16x8;
typedef __attribute__((ext_vector_type(4))) float f32x4;

__device__ inline unsigned short f2bf(float f) {
    unsigned u = __builtin_bit_cast(unsigned, f);
    unsigned r = (u + 0x7FFFu + ((u >> 16) & 1u)) >> 16;  // RTNE
    return (unsigned short)r;
}

// ---------------------------------------------------------------------------
// Kernel 1: transpose + bf16-cast the three weight matrices.
// W[p]: [DMODEL][HD] f32  ->  Wt[p]: [HD][DMODEL] bf16
// ---------------------------------------------------------------------------
__global__ void prep_w(const float* __restrict__ Wq, const float* __restrict__ Wk,
                       const float* __restrict__ Wv, unsigned short* __restrict__ Wt) {
    int p = blockIdx.x >> 4;        // 0..2
    int chunk = blockIdx.x & 15;    // 0..15 (64-wide k slices)
    const float* W = (p == 0) ? Wq : (p == 1) ? Wk : Wv;
    int kbase = chunk * 64;
    for (int i = threadIdx.x; i < 64 * 64; i += 256) {
        int h = i >> 6;
        int k = kbase + (i & 63);
        Wt[(size_t)p * HD * DMODEL + (size_t)h * DMODEL + k] = f2bf(W[(size_t)k * HD + h]);
    }
}

// ---------------------------------------------------------------------------
// Kernel 2: projections. x[16384][1024] f32 @ W -> Q,K [B*S][64] bf16, VT [B][64][S] bf16
// 4 waves/block, each wave = one 16-row m-frag, all 3 projections x 4 n-frags.
// ---------------------------------------------------------------------------
__global__ __launch_bounds__(256) void proj_kernel(
    const float* __restrict__ x,
    const float* __restrict__ bq, const float* __restrict__ bk, const float* __restrict__ bv,
    const unsigned short* __restrict__ Wt,
    unsigned short* __restrict__ Q, unsigned short* __restrict__ K,
    unsigned short* __restrict__ VT) {

    int tid = threadIdx.x;
    int w = tid >> 6, lane = tid & 63;
    int lg = lane >> 4, ln = lane & 15;

    int mrow = blockIdx.x * 64 + w * 16 + ln;            // A-frag row (= lane%16)
    const float* xrow = x + (size_t)mrow * DMODEL + lg * 8;
    const unsigned short* wb = Wt + (size_t)ln * DMODEL + lg * 8;

    f32x4 acc[3][4];
#pragma unroll
    for (int p = 0; p < 3; p++)
#pragma unroll
        for (int n = 0; n < 4; n++) acc[p][n] = (f32x4){0.f, 0.f, 0.f, 0.f};

    for (int k0 = 0; k0 < DMODEL; k0 += 32) {
        f32x4 a0 = *(const f32x4*)(xrow + k0);
        f32x4 a1 = *(const f32x4*)(xrow + k0 + 4);
        union { bf16x8 v; unsigned short u[8]; } au;
#pragma unroll
        for (int j = 0; j < 4; j++) { au.u[j] = f2bf(a0[j]); au.u[4 + j] = f2bf(a1[j]); }

#pragma unroll
        for (int p = 0; p < 3; p++) {
#pragma unroll
            for (int n = 0; n < 4; n++) {
                bf16x8 bfrag = *(const bf16x8*)(wb + (size_t)p * HD * DMODEL + n * 16 * DMODEL + k0);
                acc[p][n] = __builtin_amdgcn_mfma_f32_16x16x32_bf16(au.v, bfrag, acc[p][n], 0, 0, 0);
            }
        }
    }

    // epilogue: + bias, store (C layout: col = ln, row = lg*4 + r)
    int orow0 = blockIdx.x * 64 + w * 16 + lg * 4;
#pragma unroll
    for (int p = 0; p < 3; p++) {
        const float* bias = (p == 0) ? bq : (p == 1) ? bk : bv;
#pragma unroll
        for (int n = 0; n < 4; n++) {
            int col = n * 16 + ln;
            float bb = bias[col];
#pragma unroll
            for (int r = 0; r < 4; r++) {
                float v = acc[p][n][r] + bb;
                int row = orow0 + r;
                if (p == 0)       Q[(size_t)row * HD + col] = f2bf(v);
                else if (p == 1)  K[(size_t)row * HD + col] = f2bf(v);
                else {
                    int b = row >> 11, s = row & (SEQ - 1);
                    VT[((size_t)b * HD + col) * SEQ + s] = f2bf(v);
                }
            }
        }
    }
}

// ---------------------------------------------------------------------------
// Kernel 3: flash attention. grid (S/64, B), 4 waves x 16 q-rows, KBLK=64.
// ---------------------------------------------------------------------------
__global__ __launch_bounds__(256) void attn_kernel(
    const unsigned short* __restrict__ Q, const unsigned short* __restrict__ K,
    const unsigned short* __restrict__ VT, const int* __restrict__ mask,
    float* __restrict__ out) {

    __shared__ __align__(16) unsigned short plds[4][16][72];  // +8 pad: 2-way banks only

    int tid = threadIdx.x;
    int w = tid >> 6, lane = tid & 63;
    int lg = lane >> 4, ln = lane & 15;
    int b = blockIdx.y;
    int q0 = blockIdx.x * 64 + w * 16;

    const float SC = 0.125f * 1.44269504088896f;  // head^-0.5 * log2(e)

    bf16x8 qf[2];
    {
        const unsigned short* qptr = Q + ((size_t)b * SEQ + q0 + ln) * HD + lg * 8;
        qf[0] = *(const bf16x8*)(qptr);
        qf[1] = *(const bf16x8*)(qptr + 32);
    }

    f32x4 o[4];
#pragma unroll
    for (int n = 0; n < 4; n++) o[n] = (f32x4){0.f, 0.f, 0.f, 0.f};
    float mrun[4], lrun[4];
#pragma unroll
    for (int r = 0; r < 4; r++) { mrun[r] = -1e38f; lrun[r] = 0.f; }

    const unsigned short* Kb = K + (size_t)b * SEQ * HD;
    const unsigned short* Vb = VT + (size_t)b * HD * SEQ;
    const int* mb = mask + b * SEQ;

    for (int kt = 0; kt < SEQ; kt += 64) {
        // ---- S = Q K^T (x SC), C-layout: lane holds rows lg*4+r, col n*16+ln
        f32x4 s[4];
#pragma unroll
        for (int n = 0; n < 4; n++) {
            const unsigned short* kptr = Kb + (size_t)(kt + n * 16 + ln) * HD + lg * 8;
            bf16x8 kv0 = *(const bf16x8*)(kptr);
            bf16x8 kv1 = *(const bf16x8*)(kptr + 32);
            f32x4 z = (f32x4){0.f, 0.f, 0.f, 0.f};
            s[n] = __builtin_amdgcn_mfma_f32_16x16x32_bf16(qf[0], kv0, z, 0, 0, 0);
            s[n] = __builtin_amdgcn_mfma_f32_16x16x32_bf16(qf[1], kv1, s[n], 0, 0, 0);
        }
        // ---- scale + key-padding mask
#pragma unroll
        for (int n = 0; n < 4; n++) {
            int kc = kt + n * 16 + ln;
            bool valid = (mb[kc] != 0);
#pragma unroll
            for (int r = 0; r < 4; r++) {
                float t = s[n][r] * SC;
                s[n][r] = valid ? t : -1e30f;
            }
        }
        // ---- tile row-max (reduce 4 n-frags locally, then 16-lane group)
        float corr[4];
#pragma unroll
        for (int r = 0; r < 4; r++) {
            float v = fmaxf(fmaxf(s[0][r], s[1][r]), fmaxf(s[2][r], s[3][r]));
#pragma unroll
            for (int off = 1; off < 16; off <<= 1)
                v = fmaxf(v, __shfl_xor(v, off));
            float mnew = fmaxf(mrun[r], v);
            corr[r] = exp2f(mrun[r] - mnew);
            mrun[r] = mnew;
        }
        // ---- p = exp2(s - m); tile row-sum
        float ts[4] = {0.f, 0.f, 0.f, 0.f};
#pragma unroll
        for (int n = 0; n < 4; n++) {
#pragma unroll
            for (int r = 0; r < 4; r++) {
                float p = exp2f(s[n][r] - mrun[r]);
                s[n][r] = p;
                ts[r] += p;
            }
        }
#pragma unroll
        for (int r = 0; r < 4; r++) {
            float v = ts[r];
#pragma unroll
            for (int off = 1; off < 16; off <<= 1)
                v += __shfl_xor(v, off);
            lrun[r] = lrun[r] * corr[r] + v;
        }
        // ---- rescale O
#pragma unroll
        for (int n = 0; n < 4; n++)
#pragma unroll
            for (int r = 0; r < 4; r++) o[n][r] *= corr[r];

        // ---- P (C-layout) -> LDS -> A-layout bf16 frags (wave-private buffer)
#pragma unroll
        for (int n = 0; n < 4; n++)
#pragma unroll
            for (int r = 0; r < 4; r++)
                plds[w][lg * 4 + r][n * 16 + ln] = f2bf(s[n][r]);
        asm volatile("s_waitcnt lgkmcnt(0)" ::: "memory");
        __builtin_amdgcn_sched_barrier(0);
        bf16x8 pa0 = *(const bf16x8*)(&plds[w][ln][lg * 8]);
        bf16x8 pa1 = *(const bf16x8*)(&plds[w][ln][32 + lg * 8]);

        // ---- O += P V  (V read from VT rows: contiguous)
#pragma unroll
        for (int n = 0; n < 4; n++) {
            const unsigned short* vptr = Vb + (size_t)(n * 16 + ln) * SEQ + kt + lg * 8;
            bf16x8 v0 = *(const bf16x8*)(vptr);
            bf16x8 v1 = *(const bf16x8*)(vptr + 32);
            o[n] = __builtin_amdgcn_mfma_f32_16x16x32_bf16(pa0, v0, o[n], 0, 0, 0);
            o[n] = __builtin_amdgcn_mfma_f32_16x16x32_bf16(pa1, v1, o[n], 0, 0, 0);
        }
    }

    // ---- epilogue: O /= l, store fp32
#pragma unroll
    for (int r = 0; r < 4; r++) {
        float inv = 1.0f / lrun[r];
        int row = q0 + lg * 4 + r;
#pragma unroll
        for (int n = 0; n < 4; n++)
            out[((size_t)b * SEQ + row) * HD + n * 16 + ln] = o[n][r] * inv;
    }
}

// ---------------------------------------------------------------------------
extern "C" void kernel_launch(void* const* d_in, const int* in_sizes, int n_in,
                              void* d_out, int out_size, void* d_ws, size_t ws_size,
                              hipStream_t stream) {
    const float* x  = (const float*)d_in[0];
    const int*   am = (const int*)d_in[1];
    const float* Wq = (const float*)d_in[2];
    const float* bq = (const float*)d_in[3];
    const float* Wk = (const float*)d_in[4];
    const float* bk = (const float*)d_in[5];
    const float* Wv = (const float*)d_in[6];
    const float* bv = (const float*)d_in[7];
    float* out = (float*)d_out;

    unsigned short* ws = (unsigned short*)d_ws;
    unsigned short* Wt  = ws;                              // 3*64*1024
    unsigned short* Qw  = ws + 3 * HD * DMODEL;            // [B*S][64]
    unsigned short* Kw  = Qw + (size_t)BATCH * SEQ * HD;   // [B*S][64]
    unsigned short* VTw = Kw + (size_t)BATCH * SEQ * HD;   // [B][64][S]

    prep_w<<<48, 256, 0, stream>>>(Wq, Wk, Wv, Wt);
    proj_kernel<<<(BATCH * SEQ) / 64, 256, 0, stream>>>(x, bq, bk, bv, Wt, Qw, Kw, VTw);
    attn_kernel<<<dim3(SEQ / 64, BATCH), 256, 0, stream>>>(Qw, Kw, VTw, am, out);
}

// Round 2
// 139.465 us; speedup vs baseline: 1.0604x; 1.0604x over previous
//
#include <hip/hip_runtime.h>
#include <hip/hip_bf16.h>

#define BATCH 8
#define SEQ   2048
#define DMODEL 1024
#define HD    64

typedef __attribute__((ext_vector_type(8))) short bf16x8;
typedef __attribute__((ext_vector_type(4))) float f32x4;

__device__ inline unsigned short f2bf(float f) {
    unsigned u = __builtin_bit_cast(unsigned, f);
    unsigned r = (u + 0x7FFFu + ((u >> 16) & 1u)) >> 16;  // RTNE
    return (unsigned short)r;
}

// ---------------------------------------------------------------------------
// Kernel 1: transpose + bf16-cast the three weight matrices.
// W[p]: [DMODEL][HD] f32  ->  Wt[p]: [HD][DMODEL] bf16
// ---------------------------------------------------------------------------
__global__ void prep_w(const float* __restrict__ Wq, const float* __restrict__ Wk,
                       const float* __restrict__ Wv, unsigned short* __restrict__ Wt) {
    int p = blockIdx.x >> 4;        // 0..2
    int chunk = blockIdx.x & 15;    // 0..15 (64-wide k slices)
    const float* W = (p == 0) ? Wq : (p == 1) ? Wk : Wv;
    int kbase = chunk * 64;
    for (int i = threadIdx.x; i < 64 * 64; i += 256) {
        int h = i >> 6;
        int k = kbase + (i & 63);
        Wt[(size_t)p * HD * DMODEL + (size_t)h * DMODEL + k] = f2bf(W[(size_t)k * HD + h]);
    }
}

// ---------------------------------------------------------------------------
// Kernel 2: projections, split-K over 4 waves + LDS combine.
// Block = one 16-row m-tile; wave w accumulates K in [w*256,(w+1)*256).
// x[16384][1024] f32 @ W -> Q,K [B*S][64] bf16, VT [B][64][S] bf16
// ---------------------------------------------------------------------------
__global__ __launch_bounds__(256) void proj_kernel(
    const float* __restrict__ x,
    const float* __restrict__ bq, const float* __restrict__ bk, const float* __restrict__ bv,
    const unsigned short* __restrict__ Wt,
    unsigned short* __restrict__ Q, unsigned short* __restrict__ K,
    unsigned short* __restrict__ VT) {

    __shared__ float red[4][12][16][17];   // [wave][p*4+n][row][col16(+1 pad)]

    int tid = threadIdx.x;
    int w = tid >> 6, lane = tid & 63;
    int lg = lane >> 4, ln = lane & 15;

    int mrow = blockIdx.x * 16 + ln;                  // A-frag row (= lane%16)
    int kofs = w * 256;
    const float* xrow = x + (size_t)mrow * DMODEL + kofs + lg * 8;
    const unsigned short* wb = Wt + (size_t)ln * DMODEL + kofs + lg * 8;

    f32x4 acc[3][4];
#pragma unroll
    for (int p = 0; p < 3; p++)
#pragma unroll
        for (int n = 0; n < 4; n++) acc[p][n] = (f32x4){0.f, 0.f, 0.f, 0.f};

    for (int k0 = 0; k0 < 256; k0 += 32) {
        f32x4 a0 = *(const f32x4*)(xrow + k0);
        f32x4 a1 = *(const f32x4*)(xrow + k0 + 4);
        union { bf16x8 v; unsigned short u[8]; } au;
#pragma unroll
        for (int j = 0; j < 4; j++) { au.u[j] = f2bf(a0[j]); au.u[4 + j] = f2bf(a1[j]); }

#pragma unroll
        for (int p = 0; p < 3; p++) {
#pragma unroll
            for (int n = 0; n < 4; n++) {
                bf16x8 bfrag = *(const bf16x8*)(wb + (size_t)p * HD * DMODEL + n * 16 * DMODEL + k0);
                acc[p][n] = __builtin_amdgcn_mfma_f32_16x16x32_bf16(au.v, bfrag, acc[p][n], 0, 0, 0);
            }
        }
    }

    // partials -> LDS   (C layout: row = lg*4+r, col = n*16+ln)
#pragma unroll
    for (int p = 0; p < 3; p++)
#pragma unroll
        for (int n = 0; n < 4; n++)
#pragma unroll
            for (int r = 0; r < 4; r++)
                red[w][p * 4 + n][lg * 4 + r][ln] = acc[p][n][r];
    __syncthreads();

    // combine + bias + store: 3*16*64 = 3072 outputs, 12 per thread
    for (int i = tid; i < 3072; i += 256) {
        int p   = i >> 10;
        int rem = i & 1023;
        int row = rem >> 6;
        int col = rem & 63;
        int n = col >> 4, c = col & 15;
        float s = red[0][p * 4 + n][row][c] + red[1][p * 4 + n][row][c]
                + red[2][p * 4 + n][row][c] + red[3][p * 4 + n][row][c];
        const float* bias = (p == 0) ? bq : (p == 1) ? bk : bv;
        s += bias[col];
        int grow = blockIdx.x * 16 + row;
        if (p == 0)      Q[(size_t)grow * HD + col] = f2bf(s);
        else if (p == 1) K[(size_t)grow * HD + col] = f2bf(s);
        else {
            int b2 = grow >> 11, srow = grow & (SEQ - 1);
            VT[((size_t)b2 * HD + col) * SEQ + srow] = f2bf(s);
        }
    }
}

// ---------------------------------------------------------------------------
// Kernel 3: flash attention, split-keys over 4 waves + LDS combine.
// grid (S/16, B); block = one 16-row q-tile; wave w owns keys [w*512,(w+1)*512).
// ---------------------------------------------------------------------------
__global__ __launch_bounds__(256) void attn_kernel(
    const unsigned short* __restrict__ Q, const unsigned short* __restrict__ K,
    const unsigned short* __restrict__ VT, const int* __restrict__ mask,
    float* __restrict__ out) {

    __shared__ __align__(16) unsigned short plds[4][16][72];  // P roundtrip, wave-private
    __shared__ float po[4][16][68];                           // partial O (+4 pad)
    __shared__ float pm[4][16], pl[4][16];                    // partial max / sum

    int tid = threadIdx.x;
    int w = tid >> 6, lane = tid & 63;
    int lg = lane >> 4, ln = lane & 15;
    int b = blockIdx.y;
    int q0 = blockIdx.x * 16;

    const float SC = 0.125f * 1.44269504088896f;  // head^-0.5 * log2(e)

    bf16x8 qf[2];
    {
        const unsigned short* qptr = Q + ((size_t)b * SEQ + q0 + ln) * HD + lg * 8;
        qf[0] = *(const bf16x8*)(qptr);
        qf[1] = *(const bf16x8*)(qptr + 32);
    }

    f32x4 o[4];
#pragma unroll
    for (int n = 0; n < 4; n++) o[n] = (f32x4){0.f, 0.f, 0.f, 0.f};
    float mrun[4], lrun[4];
#pragma unroll
    for (int r = 0; r < 4; r++) { mrun[r] = -1e38f; lrun[r] = 0.f; }

    const unsigned short* Kb = K + (size_t)b * SEQ * HD;
    const unsigned short* Vb = VT + (size_t)b * HD * SEQ;
    const int* mb = mask + b * SEQ;

    int kend = w * 512 + 512;
    for (int kt = w * 512; kt < kend; kt += 64) {
        // ---- S = Q K^T (x SC), C-layout: lane holds rows lg*4+r, col n*16+ln
        f32x4 s[4];
#pragma unroll
        for (int n = 0; n < 4; n++) {
            const unsigned short* kptr = Kb + (size_t)(kt + n * 16 + ln) * HD + lg * 8;
            bf16x8 kv0 = *(const bf16x8*)(kptr);
            bf16x8 kv1 = *(const bf16x8*)(kptr + 32);
            f32x4 z = (f32x4){0.f, 0.f, 0.f, 0.f};
            s[n] = __builtin_amdgcn_mfma_f32_16x16x32_bf16(qf[0], kv0, z, 0, 0, 0);
            s[n] = __builtin_amdgcn_mfma_f32_16x16x32_bf16(qf[1], kv1, s[n], 0, 0, 0);
        }
        // ---- scale + key-padding mask
#pragma unroll
        for (int n = 0; n < 4; n++) {
            int kc = kt + n * 16 + ln;
            bool valid = (mb[kc] != 0);
#pragma unroll
            for (int r = 0; r < 4; r++) {
                float t = s[n][r] * SC;
                s[n][r] = valid ? t : -1e30f;
            }
        }
        // ---- tile row-max (4 n-frags locally, then 16-lane group reduce)
        float corr[4];
#pragma unroll
        for (int r = 0; r < 4; r++) {
            float v = fmaxf(fmaxf(s[0][r], s[1][r]), fmaxf(s[2][r], s[3][r]));
#pragma unroll
            for (int off = 1; off < 16; off <<= 1)
                v = fmaxf(v, __shfl_xor(v, off));
            float mnew = fmaxf(mrun[r], v);
            corr[r] = exp2f(mrun[r] - mnew);
            mrun[r] = mnew;
        }
        // ---- p = exp2(s - m); tile row-sum
        float ts[4] = {0.f, 0.f, 0.f, 0.f};
#pragma unroll
        for (int n = 0; n < 4; n++) {
#pragma unroll
            for (int r = 0; r < 4; r++) {
                float p = exp2f(s[n][r] - mrun[r]);
                s[n][r] = p;
                ts[r] += p;
            }
        }
#pragma unroll
        for (int r = 0; r < 4; r++) {
            float v = ts[r];
#pragma unroll
            for (int off = 1; off < 16; off <<= 1)
                v += __shfl_xor(v, off);
            lrun[r] = lrun[r] * corr[r] + v;
        }
        // ---- rescale O
#pragma unroll
        for (int n = 0; n < 4; n++)
#pragma unroll
            for (int r = 0; r < 4; r++) o[n][r] *= corr[r];

        // ---- P (C-layout) -> LDS -> A-layout bf16 frags (wave-private buffer)
#pragma unroll
        for (int n = 0; n < 4; n++)
#pragma unroll
            for (int r = 0; r < 4; r++)
                plds[w][lg * 4 + r][n * 16 + ln] = f2bf(s[n][r]);
        asm volatile("s_waitcnt lgkmcnt(0)" ::: "memory");
        __builtin_amdgcn_sched_barrier(0);
        bf16x8 pa0 = *(const bf16x8*)(&plds[w][ln][lg * 8]);
        bf16x8 pa1 = *(const bf16x8*)(&plds[w][ln][32 + lg * 8]);

        // ---- O += P V  (V read from VT rows: contiguous)
#pragma unroll
        for (int n = 0; n < 4; n++) {
            const unsigned short* vptr = Vb + (size_t)(n * 16 + ln) * SEQ + kt + lg * 8;
            bf16x8 v0 = *(const bf16x8*)(vptr);
            bf16x8 v1 = *(const bf16x8*)(vptr + 32);
            o[n] = __builtin_amdgcn_mfma_f32_16x16x32_bf16(pa0, v0, o[n], 0, 0, 0);
            o[n] = __builtin_amdgcn_mfma_f32_16x16x32_bf16(pa1, v1, o[n], 0, 0, 0);
        }
    }

    // ---- partials -> LDS
#pragma unroll
    for (int n = 0; n < 4; n++)
#pragma unroll
        for (int r = 0; r < 4; r++)
            po[w][lg * 4 + r][n * 16 + ln] = o[n][r];
    if (ln == 0) {
#pragma unroll
        for (int r = 0; r < 4; r++) {
            pm[w][lg * 4 + r] = mrun[r];
            pl[w][lg * 4 + r] = lrun[r];
        }
    }
    __syncthreads();

    // ---- combine 4 wave-partials; thread t: col = t&63, rows (t>>6)*4..+3
    {
        int col = tid & 63;
        int r0 = (tid >> 6) * 4;
#pragma unroll
        for (int rr = 0; rr < 4; rr++) {
            int row = r0 + rr;
            float m0 = pm[0][row], m1 = pm[1][row], m2 = pm[2][row], m3 = pm[3][row];
            float M = fmaxf(fmaxf(m0, m1), fmaxf(m2, m3));
            float s0 = exp2f(m0 - M), s1 = exp2f(m1 - M), s2 = exp2f(m2 - M), s3 = exp2f(m3 - M);
            float L = pl[0][row] * s0 + pl[1][row] * s1 + pl[2][row] * s2 + pl[3][row] * s3;
            float O = po[0][row][col] * s0 + po[1][row][col] * s1
                    + po[2][row][col] * s2 + po[3][row][col] * s3;
            out[((size_t)b * SEQ + q0 + row) * HD + col] = O / L;
        }
    }
}

// ---------------------------------------------------------------------------
extern "C" void kernel_launch(void* const* d_in, const int* in_sizes, int n_in,
                              void* d_out, int out_size, void* d_ws, size_t ws_size,
                              hipStream_t stream) {
    const float* x  = (const float*)d_in[0];
    const int*   am = (const int*)d_in[1];
    const float* Wq = (const float*)d_in[2];
    const float* bq = (const float*)d_in[3];
    const float* Wk = (const float*)d_in[4];
    const float* bk = (const float*)d_in[5];
    const float* Wv = (const float*)d_in[6];
    const float* bv = (const float*)d_in[7];
    float* out = (float*)d_out;

    unsigned short* ws = (unsigned short*)d_ws;
    unsigned short* Wt  = ws;                              // 3*64*1024
    unsigned short* Qw  = ws + 3 * HD * DMODEL;            // [B*S][64]
    unsigned short* Kw  = Qw + (size_t)BATCH * SEQ * HD;   // [B*S][64]
    unsigned short* VTw = Kw + (size_t)BATCH * SEQ * HD;   // [B][64][S]

    prep_w<<<48, 256, 0, stream>>>(Wq, Wk, Wv, Wt);
    proj_kernel<<<(BATCH * SEQ) / 16, 256, 0, stream>>>(x, bq, bk, bv, Wt, Qw, Kw, VTw);
    attn_kernel<<<dim3(SEQ / 16, BATCH), 256, 0, stream>>>(Qw, Kw, VTw, am, out);
}

// Round 3
// 128.936 us; speedup vs baseline: 1.1470x; 1.0817x over previous
//
#include <hip/hip_runtime.h>
#include <hip/hip_bf16.h>

#define BATCH 8
#define SEQ   2048
#define DMODEL 1024
#define HD    64

typedef __attribute__((ext_vector_type(8))) short bf16x8;
typedef __attribute__((ext_vector_type(4))) float f32x4;
typedef __attribute__((ext_vector_type(2))) unsigned uint2v;

__device__ inline unsigned short f2bf(float f) {
    unsigned u = __builtin_bit_cast(unsigned, f);
    unsigned r = (u + 0x7FFFu + ((u >> 16) & 1u)) >> 16;  // RTNE
    return (unsigned short)r;
}

__device__ inline unsigned cvtpk(float lo, float hi) {
    unsigned r;
    asm("v_cvt_pk_bf16_f32 %0, %1, %2" : "=v"(r) : "v"(lo), "v"(hi));
    return r;
}

// ---------------------------------------------------------------------------
// Kernel 1: coalesced LDS-tiled transpose + bf16 cast of the weights.
// W[p]: [DMODEL][HD] f32 -> Wt[p]: [HD][DMODEL] bf16.  Grid 48 = 3p x 16 chunks.
// ---------------------------------------------------------------------------
__global__ void prep_w(const float* __restrict__ Wq, const float* __restrict__ Wk,
                       const float* __restrict__ Wv, unsigned short* __restrict__ Wt) {
    __shared__ float t[64][65];
    int p = blockIdx.x >> 4;
    int k0 = (blockIdx.x & 15) * 64;
    const float* W = (p == 0) ? Wq : (p == 1) ? Wk : Wv;
#pragma unroll
    for (int j = 0; j < 16; j++) {
        int idx = threadIdx.x + j * 256;
        int r = idx >> 6, c = idx & 63;
        t[r][c] = W[(size_t)(k0 + r) * HD + c];      // coalesced read
    }
    __syncthreads();
#pragma unroll
    for (int j = 0; j < 16; j++) {
        int idx = threadIdx.x + j * 256;
        int h = idx >> 6, kk = idx & 63;
        Wt[(size_t)p * HD * DMODEL + (size_t)h * DMODEL + k0 + kk] = f2bf(t[kk][h]);  // coalesced write
    }
}

// ---------------------------------------------------------------------------
// Kernel 2: projections, split-K over 4 waves + LDS combine, 2-deep x prefetch.
// ---------------------------------------------------------------------------
__global__ __launch_bounds__(256) void proj_kernel(
    const float* __restrict__ x,
    const float* __restrict__ bq, const float* __restrict__ bk, const float* __restrict__ bv,
    const unsigned short* __restrict__ Wt,
    unsigned short* __restrict__ Q, unsigned short* __restrict__ K,
    unsigned short* __restrict__ VT) {

    __shared__ float red[4][12][16][17];

    int tid = threadIdx.x;
    int w = tid >> 6, lane = tid & 63;
    int lg = lane >> 4, ln = lane & 15;

    int mrow = blockIdx.x * 16 + ln;
    int kofs = w * 256;
    const float* xrow = x + (size_t)mrow * DMODEL + kofs + lg * 8;
    const unsigned short* wb = Wt + (size_t)ln * DMODEL + kofs + lg * 8;

    f32x4 acc[3][4];
#pragma unroll
    for (int p = 0; p < 3; p++)
#pragma unroll
        for (int n = 0; n < 4; n++) acc[p][n] = (f32x4){0.f, 0.f, 0.f, 0.f};

    // 2-deep register prefetch of x
    f32x4 xp0a = *(const f32x4*)(xrow + 0);
    f32x4 xp0b = *(const f32x4*)(xrow + 4);
    f32x4 xp1a = *(const f32x4*)(xrow + 32);
    f32x4 xp1b = *(const f32x4*)(xrow + 36);

#pragma unroll
    for (int s = 0; s < 8; s++) {
        int k0 = s * 32;
        f32x4 a0, a1;
        if ((s & 1) == 0) { a0 = xp0a; a1 = xp0b; } else { a0 = xp1a; a1 = xp1b; }
        if (s + 2 < 8) {
            if ((s & 1) == 0) {
                xp0a = *(const f32x4*)(xrow + (s + 2) * 32);
                xp0b = *(const f32x4*)(xrow + (s + 2) * 32 + 4);
            } else {
                xp1a = *(const f32x4*)(xrow + (s + 2) * 32);
                xp1b = *(const f32x4*)(xrow + (s + 2) * 32 + 4);
            }
        }
        union { bf16x8 v; unsigned u[4]; } au;
        au.u[0] = cvtpk(a0[0], a0[1]); au.u[1] = cvtpk(a0[2], a0[3]);
        au.u[2] = cvtpk(a1[0], a1[1]); au.u[3] = cvtpk(a1[2], a1[3]);

#pragma unroll
        for (int p = 0; p < 3; p++) {
#pragma unroll
            for (int n = 0; n < 4; n++) {
                bf16x8 bfrag = *(const bf16x8*)(wb + (size_t)p * HD * DMODEL + n * 16 * DMODEL + k0);
                acc[p][n] = __builtin_amdgcn_mfma_f32_16x16x32_bf16(au.v, bfrag, acc[p][n], 0, 0, 0);
            }
        }
    }

#pragma unroll
    for (int p = 0; p < 3; p++)
#pragma unroll
        for (int n = 0; n < 4; n++)
#pragma unroll
            for (int r = 0; r < 4; r++)
                red[w][p * 4 + n][lg * 4 + r][ln] = acc[p][n][r];
    __syncthreads();

    for (int i = tid; i < 3072; i += 256) {
        int p   = i >> 10;
        int rem = i & 1023;
        int row = rem >> 6;
        int col = rem & 63;
        int n = col >> 4, c = col & 15;
        float s = red[0][p * 4 + n][row][c] + red[1][p * 4 + n][row][c]
                + red[2][p * 4 + n][row][c] + red[3][p * 4 + n][row][c];
        const float* bias = (p == 0) ? bq : (p == 1) ? bk : bv;
        s += bias[col];
        int grow = blockIdx.x * 16 + row;
        if (p == 0)      Q[(size_t)grow * HD + col] = f2bf(s);
        else if (p == 1) K[(size_t)grow * HD + col] = f2bf(s);
        else {
            int b2 = grow >> 11, srow = grow & (SEQ - 1);
            VT[((size_t)b2 * HD + col) * SEQ + srow] = f2bf(s);
        }
    }
}

// ---------------------------------------------------------------------------
// Kernel 3: flash attention, swapped QK^T (S^T layout -> in-lane softmax),
// KBLK=128, split-keys over 4 waves, cvt_pk P-pack, defer-max, aliased LDS.
// grid (S/16, B), 4 waves x 512 keys each.
// ---------------------------------------------------------------------------
__global__ __launch_bounds__(256, 4) void attn_kernel(
    const unsigned short* __restrict__ Q, const unsigned short* __restrict__ K,
    const unsigned short* __restrict__ VT, const int* __restrict__ mask,
    float* __restrict__ out) {

    // Region A (k-loop): biasl [2048]f32 @0 (8192B), plds [4][16][136]bf16 @8192 (17408B)
    // Region B (epilogue, aliases A): po [4][16][68]f32 @0 (17408B), pm/pl @17408 (512B)
    __shared__ __align__(16) char smem[25600];
    float* biasl = (float*)smem;
    unsigned short (*plds)[16][136] = (unsigned short (*)[16][136])(smem + 8192);
    float (*po)[16][68] = (float (*)[16][68])smem;
    float (*pm)[16] = (float (*)[16])(smem + 17408);
    float (*pl)[16] = (float (*)[16])(smem + 17664);

    int tid = threadIdx.x;
    int w = tid >> 6, lane = tid & 63;
    int lg = lane >> 4, ln = lane & 15;
    int b = blockIdx.y;
    int q0 = blockIdx.x * 16;

    const float SC = 0.125f * 1.44269504088896f;  // head^-0.5 * log2(e)

    // mask -> additive bias (exp2 domain), once per block
    const int* mb = mask + b * SEQ;
    for (int i = tid; i < SEQ; i += 256)
        biasl[i] = mb[i] ? 0.f : -1e30f;
    __syncthreads();

    bf16x8 qf[2];
    {
        const unsigned short* qptr = Q + ((size_t)b * SEQ + q0 + ln) * HD + lg * 8;
        qf[0] = *(const bf16x8*)(qptr);
        qf[1] = *(const bf16x8*)(qptr + 32);
    }

    f32x4 o[4];
#pragma unroll
    for (int n = 0; n < 4; n++) o[n] = (f32x4){0.f, 0.f, 0.f, 0.f};
    float mrun = -1e38f, lrun = 0.f;

    const unsigned short* Kb = K + (size_t)b * SEQ * HD;
    const unsigned short* Vb = VT + (size_t)b * HD * SEQ;

    int kbase = w * 512;
    for (int t = 0; t < 4; ++t) {
        int kt = kbase + t * 128;

        // ---- S^T = K Q^T: lane holds S[q=ln][k = n*16 + lg*4 + r]
        f32x4 st[8];
        __builtin_amdgcn_s_setprio(1);
#pragma unroll
        for (int n = 0; n < 8; ++n) {
            const unsigned short* kp = Kb + (size_t)(kt + n * 16 + ln) * HD + lg * 8;
            bf16x8 kv0 = *(const bf16x8*)kp;
            bf16x8 kv1 = *(const bf16x8*)(kp + 32);
            f32x4 z = (f32x4){0.f, 0.f, 0.f, 0.f};
            st[n] = __builtin_amdgcn_mfma_f32_16x16x32_bf16(kv0, qf[0], z, 0, 0, 0);
            st[n] = __builtin_amdgcn_mfma_f32_16x16x32_bf16(kv1, qf[1], st[n], 0, 0, 0);
        }
        __builtin_amdgcn_s_setprio(0);

        // ---- scale + mask bias (broadcast LDS reads)
#pragma unroll
        for (int n = 0; n < 8; ++n) {
            f32x4 bv = *(const f32x4*)&biasl[kt + n * 16 + lg * 4];
#pragma unroll
            for (int r = 0; r < 4; ++r)
                st[n][r] = fmaf(st[n][r], SC, bv[r]);
        }

        // ---- row max: 32-in-lane tree + 2 shuffles
        f32x4 mx = st[0];
#pragma unroll
        for (int n = 1; n < 8; ++n)
#pragma unroll
            for (int r = 0; r < 4; ++r) mx[r] = fmaxf(mx[r], st[n][r]);
        float pmax = fmaxf(fmaxf(mx[0], mx[1]), fmaxf(mx[2], mx[3]));
        pmax = fmaxf(pmax, __shfl_xor(pmax, 16));
        pmax = fmaxf(pmax, __shfl_xor(pmax, 32));

        // ---- defer-max rescale (THR=8)
        if (!__all(pmax <= mrun + 8.f)) {
            float mnew = fmaxf(mrun, pmax);
            float corr = exp2f(mrun - mnew);
            mrun = mnew;
            lrun *= corr;
            float c0 = __shfl(corr, lg * 4 + 0);
            float c1 = __shfl(corr, lg * 4 + 1);
            float c2 = __shfl(corr, lg * 4 + 2);
            float c3 = __shfl(corr, lg * 4 + 3);
#pragma unroll
            for (int n = 0; n < 4; ++n) {
                o[n][0] *= c0; o[n][1] *= c1; o[n][2] *= c2; o[n][3] *= c3;
            }
        }

        // ---- P = exp2(S - m), in-lane sum + 2 shuffles
        f32x4 sv = (f32x4){0.f, 0.f, 0.f, 0.f};
#pragma unroll
        for (int n = 0; n < 8; ++n)
#pragma unroll
            for (int r = 0; r < 4; ++r) {
                float pp = exp2f(st[n][r] - mrun);
                st[n][r] = pp;
                sv[r] += pp;
            }
        float ts = (sv[0] + sv[1]) + (sv[2] + sv[3]);
        ts += __shfl_xor(ts, 16);
        ts += __shfl_xor(ts, 32);
        lrun += ts;

        // ---- pack to bf16, LDS roundtrip to A-frag layout
        unsigned short* prow = &plds[w][ln][0];
#pragma unroll
        for (int n = 0; n < 8; ++n) {
            uint2v ww;
            ww[0] = cvtpk(st[n][0], st[n][1]);
            ww[1] = cvtpk(st[n][2], st[n][3]);
            *(uint2v*)(prow + n * 16 + lg * 4) = ww;   // 8B store, row q=ln
        }
        asm volatile("s_waitcnt lgkmcnt(0)" ::: "memory");
        __builtin_amdgcn_sched_barrier(0);
        bf16x8 pa[4];
#pragma unroll
        for (int m = 0; m < 4; ++m)
            pa[m] = *(const bf16x8*)(prow + m * 32 + lg * 8);

        // ---- O += P V
        __builtin_amdgcn_s_setprio(1);
#pragma unroll
        for (int m = 0; m < 4; ++m) {
#pragma unroll
            for (int n = 0; n < 4; ++n) {
                const unsigned short* vptr = Vb + (size_t)(n * 16 + ln) * SEQ + kt + m * 32 + lg * 8;
                bf16x8 vf = *(const bf16x8*)vptr;
                o[n] = __builtin_amdgcn_mfma_f32_16x16x32_bf16(pa[m], vf, o[n], 0, 0, 0);
            }
        }
        __builtin_amdgcn_s_setprio(0);
    }

    // ---- epilogue: partials into region B (aliases A) after all waves finish
    __syncthreads();
#pragma unroll
    for (int n = 0; n < 4; n++)
#pragma unroll
        for (int r = 0; r < 4; r++)
            po[w][lg * 4 + r][n * 16 + ln] = o[n][r];
    if (lane < 16) {
        pm[w][ln] = mrun;
        pl[w][ln] = lrun;
    }
    __syncthreads();

    // ---- combine 4 wave-partials
    {
        int col = tid & 63;
        int r0 = (tid >> 6) * 4;
#pragma unroll
        for (int rr = 0; rr < 4; rr++) {
            int row = r0 + rr;
            float m0 = pm[0][row], m1 = pm[1][row], m2 = pm[2][row], m3 = pm[3][row];
            float M = fmaxf(fmaxf(m0, m1), fmaxf(m2, m3));
            float s0 = exp2f(m0 - M), s1 = exp2f(m1 - M), s2 = exp2f(m2 - M), s3 = exp2f(m3 - M);
            float L = pl[0][row] * s0 + pl[1][row] * s1 + pl[2][row] * s2 + pl[3][row] * s3;
            float O = po[0][row][col] * s0 + po[1][row][col] * s1
                    + po[2][row][col] * s2 + po[3][row][col] * s3;
            out[((size_t)b * SEQ + q0 + row) * HD + col] = O / L;
        }
    }
}

// ---------------------------------------------------------------------------
extern "C" void kernel_launch(void* const* d_in, const int* in_sizes, int n_in,
                              void* d_out, int out_size, void* d_ws, size_t ws_size,
                              hipStream_t stream) {
    const float* x  = (const float*)d_in[0];
    const int*   am = (const int*)d_in[1];
    const float* Wq = (const float*)d_in[2];
    const float* bq = (const float*)d_in[3];
    const float* Wk = (const float*)d_in[4];
    const float* bk = (const float*)d_in[5];
    const float* Wv = (const float*)d_in[6];
    const float* bv = (const float*)d_in[7];
    float* out = (float*)d_out;

    unsigned short* ws = (unsigned short*)d_ws;
    unsigned short* Wt  = ws;
    unsigned short* Qw  = ws + 3 * HD * DMODEL;
    unsigned short* Kw  = Qw + (size_t)BATCH * SEQ * HD;
    unsigned short* VTw = Kw + (size_t)BATCH * SEQ * HD;

    prep_w<<<48, 256, 0, stream>>>(Wq, Wk, Wv, Wt);
    proj_kernel<<<(BATCH * SEQ) / 16, 256, 0, stream>>>(x, bq, bk, bv, Wt, Qw, Kw, VTw);
    attn_kernel<<<dim3(SEQ / 16, BATCH), 256, 0, stream>>>(Qw, Kw, VTw, am, out);
}

// Round 4
// 100.551 us; speedup vs baseline: 1.4708x; 1.2823x over previous
//
#include <hip/hip_runtime.h>
#include <hip/hip_bf16.h>

#define BATCH 8
#define SEQ   2048
#define DMODEL 1024
#define HD    64

typedef __attribute__((ext_vector_type(8))) short bf16x8;
typedef __attribute__((ext_vector_type(4))) float f32x4;
typedef __attribute__((ext_vector_type(2))) unsigned uint2v;
typedef unsigned int u32;

__device__ inline unsigned short f2bf(float f) {
    unsigned u = __builtin_bit_cast(unsigned, f);
    unsigned r = (u + 0x7FFFu + ((u >> 16) & 1u)) >> 16;  // RTNE
    return (unsigned short)r;
}

__device__ inline unsigned cvtpk(float lo, float hi) {
    unsigned r;
    asm("v_cvt_pk_bf16_f32 %0, %1, %2" : "=v"(r) : "v"(lo), "v"(hi));
    return r;
}

// async global->LDS, 16B per lane; LDS dest must be linear (base + lane*16)
__device__ inline void gl_lds16(const void* g, void* l) {
    __builtin_amdgcn_global_load_lds(
        (const __attribute__((address_space(1))) u32*)g,
        (__attribute__((address_space(3))) u32*)l, 16, 0, 0);
}

// ---------------------------------------------------------------------------
// Kernel 1: coalesced LDS-tiled transpose + bf16 cast of the weights.
// ---------------------------------------------------------------------------
__global__ void prep_w(const float* __restrict__ Wq, const float* __restrict__ Wk,
                       const float* __restrict__ Wv, unsigned short* __restrict__ Wt) {
    __shared__ float t[64][65];
    int p = blockIdx.x >> 4;
    int k0 = (blockIdx.x & 15) * 64;
    const float* W = (p == 0) ? Wq : (p == 1) ? Wk : Wv;
#pragma unroll
    for (int j = 0; j < 16; j++) {
        int idx = threadIdx.x + j * 256;
        int r = idx >> 6, c = idx & 63;
        t[r][c] = W[(size_t)(k0 + r) * HD + c];
    }
    __syncthreads();
#pragma unroll
    for (int j = 0; j < 16; j++) {
        int idx = threadIdx.x + j * 256;
        int h = idx >> 6, kk = idx & 63;
        Wt[(size_t)p * HD * DMODEL + (size_t)h * DMODEL + k0 + kk] = f2bf(t[kk][h]);
    }
}

// ---------------------------------------------------------------------------
// Kernel 2: projections. Block = 16 m-rows; 4 waves split N (3 frags each).
// x staged per 128-col chunk through LDS (coalesced + XOR-swizzled), dbuf.
// ---------------------------------------------------------------------------
__global__ __launch_bounds__(256, 4) void proj_kernel(
    const float* __restrict__ x,
    const float* __restrict__ bq, const float* __restrict__ bk, const float* __restrict__ bv,
    const unsigned short* __restrict__ Wt,
    unsigned short* __restrict__ Q, unsigned short* __restrict__ K,
    unsigned short* __restrict__ VT) {

    __shared__ unsigned short xt[2][16 * 128];   // [16 rows][128 cols] bf16, swizzled, 4KB each

    int tid = threadIdx.x;
    int w = tid >> 6, lane = tid & 63;
    int lg = lane >> 4, ln = lane & 15;
    int m0 = blockIdx.x * 16;

    // wave's 3 n-frags (f = 3w+j): p = f>>2, n = f&3
    const unsigned short* Wb[3];
#pragma unroll
    for (int j = 0; j < 3; j++) {
        int f = w * 3 + j;
        int p = f >> 2, n = f & 3;
        Wb[j] = Wt + (size_t)p * HD * DMODEL + (size_t)(n * 16 + ln) * DMODEL + lg * 8;
    }

    f32x4 acc[3];
#pragma unroll
    for (int j = 0; j < 3; j++) acc[j] = (f32x4){0.f, 0.f, 0.f, 0.f};

    // staging geometry: per chunk, thread covers 2 x f32x4; flat byte f=(tid+i*256)*16
    int row_[2], cb_[2];
#pragma unroll
    for (int i = 0; i < 2; i++) {
        int fb = (tid + i * 256) * 16;
        row_[i] = fb >> 9;          // 512B per row-chunk
        cb_[i] = fb & 511;          // byte within row-chunk
    }

    // prologue: chunk 0
    f32x4 xr[2];
#pragma unroll
    for (int i = 0; i < 2; i++)
        xr[i] = *(const f32x4*)(x + (size_t)(m0 + row_[i]) * DMODEL + (cb_[i] >> 2));
#pragma unroll
    for (int i = 0; i < 2; i++) {
        uint2v pk;
        pk[0] = cvtpk(xr[i][0], xr[i][1]);
        pk[1] = cvtpk(xr[i][2], xr[i][3]);
        int byte = (row_[i] * 256 + (cb_[i] >> 1)) ^ ((row_[i] & 7) << 4);
        *(uint2v*)((char*)&xt[0][0] + byte) = pk;
    }
    __syncthreads();

#pragma unroll
    for (int c = 0; c < 8; c++) {
        if (c < 7) {
#pragma unroll
            for (int i = 0; i < 2; i++)
                xr[i] = *(const f32x4*)(x + (size_t)(m0 + row_[i]) * DMODEL + (c + 1) * 128 + (cb_[i] >> 2));
        }
        const char* xb = (const char*)&xt[c & 1][0];
#pragma unroll
        for (int s = 0; s < 4; s++) {
            bf16x8 a = *(const bf16x8*)(xb + ((ln * 256 + s * 64 + lg * 16) ^ ((ln & 7) << 4)));
#pragma unroll
            for (int j = 0; j < 3; j++) {
                bf16x8 bfr = *(const bf16x8*)(Wb[j] + c * 128 + s * 32);
                acc[j] = __builtin_amdgcn_mfma_f32_16x16x32_bf16(a, bfr, acc[j], 0, 0, 0);
            }
        }
        if (c < 7) {
#pragma unroll
            for (int i = 0; i < 2; i++) {
                uint2v pk;
                pk[0] = cvtpk(xr[i][0], xr[i][1]);
                pk[1] = cvtpk(xr[i][2], xr[i][3]);
                int byte = (row_[i] * 256 + (cb_[i] >> 1)) ^ ((row_[i] & 7) << 4);
                *(uint2v*)((char*)&xt[(c + 1) & 1][0] + byte) = pk;
            }
        }
        __syncthreads();
    }

    // epilogue: direct store, each wave owns its 3 frags
#pragma unroll
    for (int j = 0; j < 3; j++) {
        int f = w * 3 + j;
        int p = f >> 2, n = f & 3;
        int col = n * 16 + ln;
        const float* bias = (p == 0) ? bq : (p == 1) ? bk : bv;
        float bb = bias[col];
#pragma unroll
        for (int r = 0; r < 4; r++) {
            float v = acc[j][r] + bb;
            int grow = m0 + lg * 4 + r;
            if (p == 0)      Q[(size_t)grow * HD + col] = f2bf(v);
            else if (p == 1) K[(size_t)grow * HD + col] = f2bf(v);
            else {
                int b2 = grow >> 11, srow = grow & (SEQ - 1);
                VT[((size_t)b2 * HD + col) * SEQ + srow] = f2bf(v);
            }
        }
    }
}

// ---------------------------------------------------------------------------
// Kernel 3: flash attention. Block = 64 q-rows (4 waves x 16), grid (32, 8).
// K/V tiles (KBLK=64) staged in LDS via global_load_lds with pre-swizzled
// source; XOR-swizzled reads; double-buffered; swapped-QK^T in-lane softmax.
// ---------------------------------------------------------------------------
__device__ inline void stage_tile(int tid, const unsigned short* Kb, const unsigned short* VTb,
                                  int kt, unsigned short* kbuf, unsigned short* vbuf) {
#pragma unroll
    for (int i = 0; i < 2; i++) {
        int d = tid * 16 + i * 4096;              // byte in 8KB K tile
        int row = d >> 7, slot = (d >> 4) & 7;    // row = key, 8x16B slots per 128B row
        const unsigned short* src = Kb + (size_t)(kt + row) * HD + ((slot ^ (row & 7)) << 3);
        gl_lds16(src, (char*)kbuf + d);
    }
#pragma unroll
    for (int i = 0; i < 2; i++) {
        int d = tid * 16 + i * 4096;              // byte in 8KB V tile
        int row = d >> 7, slot = (d >> 4) & 7;    // row = v-col
        const unsigned short* src = VTb + (size_t)row * SEQ + kt + ((slot ^ (row & 7)) << 3);
        gl_lds16(src, (char*)vbuf + d);
    }
}

__global__ __launch_bounds__(256, 2) void attn_kernel(
    const unsigned short* __restrict__ Q, const unsigned short* __restrict__ K,
    const unsigned short* __restrict__ VT, const int* __restrict__ mask,
    float* __restrict__ out) {

    __shared__ __align__(16) unsigned short Kls[2][64 * 64];   // 8KB each
    __shared__ __align__(16) unsigned short Vls[2][64 * 64];   // 8KB each
    __shared__ __align__(16) unsigned short plds_[4][16 * 64]; // 2KB per wave
    __shared__ float biasl[SEQ];                               // 8KB

    int tid = threadIdx.x;
    int w = tid >> 6, lane = tid & 63;
    int lg = lane >> 4, ln = lane & 15;
    int b = blockIdx.y;
    int q0 = blockIdx.x * 64 + w * 16;

    const float SC = 0.125f * 1.44269504088896f;  // head^-0.5 * log2(e)

    const int* mb = mask + b * SEQ;
    for (int i = tid; i < SEQ; i += 256)
        biasl[i] = mb[i] ? 0.f : -1e30f;

    bf16x8 qf[2];
    {
        const unsigned short* qptr = Q + ((size_t)b * SEQ + q0 + ln) * HD + lg * 8;
        qf[0] = *(const bf16x8*)(qptr);
        qf[1] = *(const bf16x8*)(qptr + 32);
    }

    f32x4 o[4];
#pragma unroll
    for (int n = 0; n < 4; n++) o[n] = (f32x4){0.f, 0.f, 0.f, 0.f};
    float mrun = -1e38f, lrun = 0.f;

    const unsigned short* Kb = K + (size_t)b * SEQ * HD;
    const unsigned short* VTb = VT + (size_t)b * HD * SEQ;

    unsigned short* kcur = &Kls[0][0]; unsigned short* knx = &Kls[1][0];
    unsigned short* vcur = &Vls[0][0]; unsigned short* vnx = &Vls[1][0];
    char* pl = (char*)&plds_[w][0];
    const int swz = (ln & 7) << 4;

    stage_tile(tid, Kb, VTb, 0, kcur, vcur);
    __syncthreads();

#pragma unroll 2
    for (int t = 0; t < 32; ++t) {
        int kt = t * 64;
        if (t < 31) stage_tile(tid, Kb, VTb, kt + 64, knx, vnx);

        // ---- S^T = K Q^T: lane holds S[key = n*16+lg*4+r][q = ln]
        f32x4 st[4];
        const char* kb = (const char*)kcur;
        __builtin_amdgcn_s_setprio(1);
#pragma unroll
        for (int n = 0; n < 4; ++n) {
            int rb = (n * 16 + ln) * 128;
            bf16x8 ka0 = *(const bf16x8*)(kb + ((rb + lg * 16) ^ swz));
            bf16x8 ka1 = *(const bf16x8*)(kb + ((rb + 64 + lg * 16) ^ swz));
            f32x4 z = (f32x4){0.f, 0.f, 0.f, 0.f};
            st[n] = __builtin_amdgcn_mfma_f32_16x16x32_bf16(ka0, qf[0], z, 0, 0, 0);
            st[n] = __builtin_amdgcn_mfma_f32_16x16x32_bf16(ka1, qf[1], st[n], 0, 0, 0);
        }
        __builtin_amdgcn_s_setprio(0);

        // ---- scale + mask bias
#pragma unroll
        for (int n = 0; n < 4; ++n) {
            f32x4 bv4 = *(const f32x4*)&biasl[kt + n * 16 + lg * 4];
#pragma unroll
            for (int r = 0; r < 4; ++r)
                st[n][r] = fmaf(st[n][r], SC, bv4[r]);
        }

        // ---- row max (16 in-lane + 2 shuffles)
        f32x4 mx = st[0];
#pragma unroll
        for (int n = 1; n < 4; ++n)
#pragma unroll
            for (int r = 0; r < 4; ++r) mx[r] = fmaxf(mx[r], st[n][r]);
        float pmax = fmaxf(fmaxf(mx[0], mx[1]), fmaxf(mx[2], mx[3]));
        pmax = fmaxf(pmax, __shfl_xor(pmax, 16));
        pmax = fmaxf(pmax, __shfl_xor(pmax, 32));

        // ---- defer-max rescale (THR=8)
        if (!__all(pmax <= mrun + 8.f)) {
            float mnew = fmaxf(mrun, pmax);
            float corr = exp2f(mrun - mnew);
            mrun = mnew;
            lrun *= corr;
            float c0 = __shfl(corr, lg * 4 + 0);
            float c1 = __shfl(corr, lg * 4 + 1);
            float c2 = __shfl(corr, lg * 4 + 2);
            float c3 = __shfl(corr, lg * 4 + 3);
#pragma unroll
            for (int n = 0; n < 4; ++n) {
                o[n][0] *= c0; o[n][1] *= c1; o[n][2] *= c2; o[n][3] *= c3;
            }
        }

        // ---- P = exp2(S - m), in-lane sum + 2 shuffles
        f32x4 sv = (f32x4){0.f, 0.f, 0.f, 0.f};
#pragma unroll
        for (int n = 0; n < 4; ++n)
#pragma unroll
            for (int r = 0; r < 4; ++r) {
                float pp = exp2f(st[n][r] - mrun);
                st[n][r] = pp;
                sv[r] += pp;
            }
        float ts = (sv[0] + sv[1]) + (sv[2] + sv[3]);
        ts += __shfl_xor(ts, 16);
        ts += __shfl_xor(ts, 32);
        lrun += ts;

        // ---- pack P -> plds (swizzled), read back as A-frags
#pragma unroll
        for (int n = 0; n < 4; ++n) {
            uint2v ww;
            ww[0] = cvtpk(st[n][0], st[n][1]);
            ww[1] = cvtpk(st[n][2], st[n][3]);
            *(uint2v*)(pl + ((ln * 128 + n * 32 + lg * 8) ^ swz)) = ww;
        }
        asm volatile("s_waitcnt lgkmcnt(0)" ::: "memory");
        __builtin_amdgcn_sched_barrier(0);
        bf16x8 pa0 = *(const bf16x8*)(pl + ((ln * 128 + lg * 16) ^ swz));
        bf16x8 pa1 = *(const bf16x8*)(pl + ((ln * 128 + 64 + lg * 16) ^ swz));

        // ---- O += P V
        const char* vb = (const char*)vcur;
        __builtin_amdgcn_s_setprio(1);
#pragma unroll
        for (int n = 0; n < 4; ++n) {
            int rb = (n * 16 + ln) * 128;
            bf16x8 v0 = *(const bf16x8*)(vb + ((rb + lg * 16) ^ swz));
            bf16x8 v1 = *(const bf16x8*)(vb + ((rb + 64 + lg * 16) ^ swz));
            o[n] = __builtin_amdgcn_mfma_f32_16x16x32_bf16(pa0, v0, o[n], 0, 0, 0);
            o[n] = __builtin_amdgcn_mfma_f32_16x16x32_bf16(pa1, v1, o[n], 0, 0, 0);
        }
        __builtin_amdgcn_s_setprio(0);

        __syncthreads();
        unsigned short* tk = kcur; kcur = knx; knx = tk;
        unsigned short* tv = vcur; vcur = vnx; vnx = tv;
    }

    // ---- epilogue: direct store (wave owns its 16 q-rows)
#pragma unroll
    for (int r = 0; r < 4; r++) {
        float Lr = __shfl(lrun, lg * 4 + r);
        float inv = 1.0f / Lr;
        int row = q0 + lg * 4 + r;
#pragma unroll
        for (int n = 0; n < 4; n++)
            out[((size_t)b * SEQ + row) * HD + n * 16 + ln] = o[n][r] * inv;
    }
}

// ---------------------------------------------------------------------------
extern "C" void kernel_launch(void* const* d_in, const int* in_sizes, int n_in,
                              void* d_out, int out_size, void* d_ws, size_t ws_size,
                              hipStream_t stream) {
    const float* x  = (const float*)d_in[0];
    const int*   am = (const int*)d_in[1];
    const float* Wq = (const float*)d_in[2];
    const float* bq = (const float*)d_in[3];
    const float* Wk = (const float*)d_in[4];
    const float* bk = (const float*)d_in[5];
    const float* Wv = (const float*)d_in[6];
    const float* bv = (const float*)d_in[7];
    float* out = (float*)d_out;

    unsigned short* ws = (unsigned short*)d_ws;
    unsigned short* Wt  = ws;
    unsigned short* Qw  = ws + 3 * HD * DMODEL;
    unsigned short* Kw  = Qw + (size_t)BATCH * SEQ * HD;
    unsigned short* VTw = Kw + (size_t)BATCH * SEQ * HD;

    prep_w<<<48, 256, 0, stream>>>(Wq, Wk, Wv, Wt);
    proj_kernel<<<(BATCH * SEQ) / 16, 256, 0, stream>>>(x, bq, bk, bv, Wt, Qw, Kw, VTw);
    attn_kernel<<<dim3(SEQ / 64, BATCH), 256, 0, stream>>>(Qw, Kw, VTw, am, out);
}

// Round 5
// 80.178 us; speedup vs baseline: 1.8445x; 1.2541x over previous
//
#include <hip/hip_runtime.h>
#include <hip/hip_bf16.h>

#define BATCH 8
#define SEQ   2048
#define DMODEL 1024
#define HD    64

typedef __attribute__((ext_vector_type(8))) short bf16x8;
typedef __attribute__((ext_vector_type(4))) float f32x4;
typedef __attribute__((ext_vector_type(2))) unsigned uint2v;
typedef unsigned int u32;

__device__ inline unsigned short f2bf(float f) {
    unsigned u = __builtin_bit_cast(unsigned, f);
    unsigned r = (u + 0x7FFFu + ((u >> 16) & 1u)) >> 16;  // RTNE
    return (unsigned short)r;
}

__device__ inline unsigned cvtpk(float lo, float hi) {
    unsigned r;
    asm("v_cvt_pk_bf16_f32 %0, %1, %2" : "=v"(r) : "v"(lo), "v"(hi));
    return r;
}

// async global->LDS, 16B per lane; LDS dest must be linear (base + lane*16)
__device__ inline void gl_lds16(const void* g, void* l) {
    __builtin_amdgcn_global_load_lds(
        (const __attribute__((address_space(1))) u32*)g,
        (__attribute__((address_space(3))) u32*)l, 16, 0, 0);
}

// ---------------------------------------------------------------------------
// Kernel 1: coalesced LDS-tiled transpose + bf16 cast of the weights.
// W[p]: [DMODEL][HD] f32 -> Wt[p]: [HD][DMODEL] bf16
// ---------------------------------------------------------------------------
__global__ void prep_w(const float* __restrict__ Wq, const float* __restrict__ Wk,
                       const float* __restrict__ Wv, unsigned short* __restrict__ Wt) {
    __shared__ float t[64][65];
    int p = blockIdx.x >> 4;
    int k0 = (blockIdx.x & 15) * 64;
    const float* W = (p == 0) ? Wq : (p == 1) ? Wk : Wv;
#pragma unroll
    for (int j = 0; j < 16; j++) {
        int idx = threadIdx.x + j * 256;
        int r = idx >> 6, c = idx & 63;
        t[r][c] = W[(size_t)(k0 + r) * HD + c];
    }
    __syncthreads();
#pragma unroll
    for (int j = 0; j < 16; j++) {
        int idx = threadIdx.x + j * 256;
        int h = idx >> 6, kk = idx & 63;
        Wt[(size_t)p * HD * DMODEL + (size_t)h * DMODEL + k0 + kk] = f2bf(t[kk][h]);
    }
}

// ---------------------------------------------------------------------------
// Kernel 2: projections as tiled GEMM. BM=64, BN=192(all), K_STEP=64.
// Grid 256 (1 block/CU), 4 waves; wave = 4 m-frags x 3 n-frags (N-split).
// x: f32 -> regs (2-step-deep prefetch) -> cvt_pk -> swizzled LDS (8KB/buf).
// W: bf16 -> regs (1-step prefetch) -> swizzled LDS (24KB/buf). Dbuf = 64KB.
// ---------------------------------------------------------------------------
__global__ __launch_bounds__(256) void proj_kernel(
    const float* __restrict__ x,
    const float* __restrict__ bq, const float* __restrict__ bk, const float* __restrict__ bv,
    const unsigned short* __restrict__ Wt,
    unsigned short* __restrict__ Q, unsigned short* __restrict__ K,
    unsigned short* __restrict__ VT) {

    __shared__ __align__(16) unsigned short Wls[2][192 * 64];  // 24KB each
    __shared__ __align__(16) unsigned short Xls[2][64 * 64];   // 8KB each

    int tid = threadIdx.x;
    int w = tid >> 6, lane = tid & 63;
    int lg = lane >> 4, ln = lane & 15;
    int m0 = blockIdx.x * 64;

    // ---- staging geometry ----
    // x: thread covers 4 rows (xrow + i*16), 16B f32 each, cols (tid&15)*4
    int xrow = tid >> 4;
    int xcolf = (tid & 15) * 4;               // f32 element col
    // W: thread covers 6 chunks d = tid*16 + i*4096: row=d>>7, slot=(d>>4)&7
    f32x4 xr0[4], xr1[4];                     // 2-deep x prefetch sets
    bf16x8 wr[6];                             // W prefetch set

    auto loadX = [&](f32x4* xr, int k0) {
#pragma unroll
        for (int i = 0; i < 4; i++)
            xr[i] = *(const f32x4*)(x + (size_t)(m0 + xrow + i * 16) * DMODEL + k0 + xcolf);
    };
    auto writeX = [&](unsigned short* buf, const f32x4* xr) {
#pragma unroll
        for (int i = 0; i < 4; i++) {
            int row = xrow + i * 16;
            uint2v pk;
            pk[0] = cvtpk(xr[i][0], xr[i][1]);
            pk[1] = cvtpk(xr[i][2], xr[i][3]);
            int slot = (tid & 15) >> 1;
            int byte = row * 128 + ((slot ^ (row & 7)) << 4) + (tid & 1) * 8;
            *(uint2v*)((char*)buf + byte) = pk;
        }
    };
    auto loadW = [&](int k0) {
#pragma unroll
        for (int i = 0; i < 6; i++) {
            int d = tid * 16 + i * 4096;
            int row = d >> 7, slot = (d >> 4) & 7;
            wr[i] = *(const bf16x8*)(Wt + (size_t)row * DMODEL + k0 + slot * 8);
        }
    };
    auto writeW = [&](unsigned short* buf) {
#pragma unroll
        for (int i = 0; i < 6; i++) {
            int d = tid * 16 + i * 4096;
            int row = d >> 7, slot = (d >> 4) & 7;
            *(bf16x8*)((char*)buf + row * 128 + ((slot ^ (row & 7)) << 4)) = wr[i];
        }
    };

    f32x4 acc[4][3];
#pragma unroll
    for (int m = 0; m < 4; m++)
#pragma unroll
        for (int j = 0; j < 3; j++) acc[m][j] = (f32x4){0.f, 0.f, 0.f, 0.f};

    // ---- prologue: step0 staged, x prefetched 2 deep, W for step1 loaded
    loadX(xr0, 0);
    loadW(0);
    writeX(&Xls[0][0], xr0);
    writeW(&Wls[0][0]);
    loadX(xr1, 64);      // step 1
    loadX(xr0, 128);     // step 2
    loadW(64);           // step 1
    __syncthreads();

    for (int t = 0; t < 16; t++) {
        int cur = t & 1;
        const char* xb = (const char*)&Xls[cur][0];
        const char* wb = (const char*)&Wls[cur][0];

#pragma unroll
        for (int s = 0; s < 2; s++) {
            bf16x8 a[4], bfr[3];
#pragma unroll
            for (int m = 0; m < 4; m++) {
                int row = m * 16 + ln;
                a[m] = *(const bf16x8*)(xb + row * 128 + (((s * 4 + lg) ^ (row & 7)) << 4));
            }
#pragma unroll
            for (int j = 0; j < 3; j++) {
                int row = (w * 3 + j) * 16 + ln;
                bfr[j] = *(const bf16x8*)(wb + row * 128 + (((s * 4 + lg) ^ (row & 7)) << 4));
            }
            __builtin_amdgcn_s_setprio(1);
#pragma unroll
            for (int m = 0; m < 4; m++)
#pragma unroll
                for (int j = 0; j < 3; j++)
                    acc[m][j] = __builtin_amdgcn_mfma_f32_16x16x32_bf16(a[m], bfr[j], acc[m][j], 0, 0, 0);
            __builtin_amdgcn_s_setprio(0);
        }

        if (t < 15) {
            // write step t+1 tiles into the other buffer
            writeX(&Xls[cur ^ 1][0], ((t + 1) & 1) ? xr1 : xr0);
            writeW(&Wls[cur ^ 1][0]);
            if (t < 14) loadW((t + 2) * 64);
            if (t < 13) loadX(((t + 1) & 1) ? xr1 : xr0, (t + 3) * 64);
        }
        __syncthreads();
    }

    // ---- epilogue: direct store; wave owns 3 n-frags over all 64 m-rows
#pragma unroll
    for (int j = 0; j < 3; j++) {
        int f = w * 3 + j;
        int p = f >> 2, n = f & 3;
        int col = n * 16 + ln;
        const float* bias = (p == 0) ? bq : (p == 1) ? bk : bv;
        float bb = bias[col];
#pragma unroll
        for (int m = 0; m < 4; m++) {
#pragma unroll
            for (int r = 0; r < 4; r++) {
                float v = acc[m][j][r] + bb;
                int grow = m0 + m * 16 + lg * 4 + r;
                if (p == 0)      Q[(size_t)grow * HD + col] = f2bf(v);
                else if (p == 1) K[(size_t)grow * HD + col] = f2bf(v);
                else {
                    int b2 = grow >> 11, srow = grow & (SEQ - 1);
                    VT[((size_t)b2 * HD + col) * SEQ + srow] = f2bf(v);
                }
            }
        }
    }
}

// ---------------------------------------------------------------------------
// Kernel 3: flash attention. Block = 64 q-rows (4 waves x 16), grid (32, 8).
// K/V tiles (KBLK=64) staged in LDS via global_load_lds with pre-swizzled
// source; XOR-swizzled reads; double-buffered; swapped-QK^T in-lane softmax.
// ---------------------------------------------------------------------------
__device__ inline void stage_tile(int tid, const unsigned short* Kb, const unsigned short* VTb,
                                  int kt, unsigned short* kbuf, unsigned short* vbuf) {
#pragma unroll
    for (int i = 0; i < 2; i++) {
        int d = tid * 16 + i * 4096;
        int row = d >> 7, slot = (d >> 4) & 7;
        const unsigned short* src = Kb + (size_t)(kt + row) * HD + ((slot ^ (row & 7)) << 3);
        gl_lds16(src, (char*)kbuf + d);
    }
#pragma unroll
    for (int i = 0; i < 2; i++) {
        int d = tid * 16 + i * 4096;
        int row = d >> 7, slot = (d >> 4) & 7;
        const unsigned short* src = VTb + (size_t)row * SEQ + kt + ((slot ^ (row & 7)) << 3);
        gl_lds16(src, (char*)vbuf + d);
    }
}

__global__ __launch_bounds__(256, 2) void attn_kernel(
    const unsigned short* __restrict__ Q, const unsigned short* __restrict__ K,
    const unsigned short* __restrict__ VT, const int* __restrict__ mask,
    float* __restrict__ out) {

    __shared__ __align__(16) unsigned short Kls[2][64 * 64];
    __shared__ __align__(16) unsigned short Vls[2][64 * 64];
    __shared__ __align__(16) unsigned short plds_[4][16 * 64];
    __shared__ float biasl[SEQ];

    int tid = threadIdx.x;
    int w = tid >> 6, lane = tid & 63;
    int lg = lane >> 4, ln = lane & 15;
    int b = blockIdx.y;
    int q0 = blockIdx.x * 64 + w * 16;

    const float SC = 0.125f * 1.44269504088896f;

    const int* mb = mask + b * SEQ;
    for (int i = tid; i < SEQ; i += 256)
        biasl[i] = mb[i] ? 0.f : -1e30f;

    bf16x8 qf[2];
    {
        const unsigned short* qptr = Q + ((size_t)b * SEQ + q0 + ln) * HD + lg * 8;
        qf[0] = *(const bf16x8*)(qptr);
        qf[1] = *(const bf16x8*)(qptr + 32);
    }

    f32x4 o[4];
#pragma unroll
    for (int n = 0; n < 4; n++) o[n] = (f32x4){0.f, 0.f, 0.f, 0.f};
    float mrun = -1e38f, lrun = 0.f;

    const unsigned short* Kb = K + (size_t)b * SEQ * HD;
    const unsigned short* VTb = VT + (size_t)b * HD * SEQ;

    unsigned short* kcur = &Kls[0][0]; unsigned short* knx = &Kls[1][0];
    unsigned short* vcur = &Vls[0][0]; unsigned short* vnx = &Vls[1][0];
    char* pl = (char*)&plds_[w][0];
    const int swz = (ln & 7) << 4;

    stage_tile(tid, Kb, VTb, 0, kcur, vcur);
    __syncthreads();

#pragma unroll 2
    for (int t = 0; t < 32; ++t) {
        int kt = t * 64;
        if (t < 31) stage_tile(tid, Kb, VTb, kt + 64, knx, vnx);

        f32x4 st[4];
        const char* kb = (const char*)kcur;
        __builtin_amdgcn_s_setprio(1);
#pragma unroll
        for (int n = 0; n < 4; ++n) {
            int rb = (n * 16 + ln) * 128;
            bf16x8 ka0 = *(const bf16x8*)(kb + ((rb + lg * 16) ^ swz));
            bf16x8 ka1 = *(const bf16x8*)(kb + ((rb + 64 + lg * 16) ^ swz));
            f32x4 z = (f32x4){0.f, 0.f, 0.f, 0.f};
            st[n] = __builtin_amdgcn_mfma_f32_16x16x32_bf16(ka0, qf[0], z, 0, 0, 0);
            st[n] = __builtin_amdgcn_mfma_f32_16x16x32_bf16(ka1, qf[1], st[n], 0, 0, 0);
        }
        __builtin_amdgcn_s_setprio(0);

#pragma unroll
        for (int n = 0; n < 4; ++n) {
            f32x4 bv4 = *(const f32x4*)&biasl[kt + n * 16 + lg * 4];
#pragma unroll
            for (int r = 0; r < 4; ++r)
                st[n][r] = fmaf(st[n][r], SC, bv4[r]);
        }

        f32x4 mx = st[0];
#pragma unroll
        for (int n = 1; n < 4; ++n)
#pragma unroll
            for (int r = 0; r < 4; ++r) mx[r] = fmaxf(mx[r], st[n][r]);
        float pmax = fmaxf(fmaxf(mx[0], mx[1]), fmaxf(mx[2], mx[3]));
        pmax = fmaxf(pmax, __shfl_xor(pmax, 16));
        pmax = fmaxf(pmax, __shfl_xor(pmax, 32));

        if (!__all(pmax <= mrun + 8.f)) {
            float mnew = fmaxf(mrun, pmax);
            float corr = exp2f(mrun - mnew);
            mrun = mnew;
            lrun *= corr;
            float c0 = __shfl(corr, lg * 4 + 0);
            float c1 = __shfl(corr, lg * 4 + 1);
            float c2 = __shfl(corr, lg * 4 + 2);
            float c3 = __shfl(corr, lg * 4 + 3);
#pragma unroll
            for (int n = 0; n < 4; ++n) {
                o[n][0] *= c0; o[n][1] *= c1; o[n][2] *= c2; o[n][3] *= c3;
            }
        }

        f32x4 sv = (f32x4){0.f, 0.f, 0.f, 0.f};
#pragma unroll
        for (int n = 0; n < 4; ++n)
#pragma unroll
            for (int r = 0; r < 4; ++r) {
                float pp = exp2f(st[n][r] - mrun);
                st[n][r] = pp;
                sv[r] += pp;
            }
        float ts = (sv[0] + sv[1]) + (sv[2] + sv[3]);
        ts += __shfl_xor(ts, 16);
        ts += __shfl_xor(ts, 32);
        lrun += ts;

#pragma unroll
        for (int n = 0; n < 4; ++n) {
            uint2v ww;
            ww[0] = cvtpk(st[n][0], st[n][1]);
            ww[1] = cvtpk(st[n][2], st[n][3]);
            *(uint2v*)(pl + ((ln * 128 + n * 32 + lg * 8) ^ swz)) = ww;
        }
        asm volatile("s_waitcnt lgkmcnt(0)" ::: "memory");
        __builtin_amdgcn_sched_barrier(0);
        bf16x8 pa0 = *(const bf16x8*)(pl + ((ln * 128 + lg * 16) ^ swz));
        bf16x8 pa1 = *(const bf16x8*)(pl + ((ln * 128 + 64 + lg * 16) ^ swz));

        const char* vb = (const char*)vcur;
        __builtin_amdgcn_s_setprio(1);
#pragma unroll
        for (int n = 0; n < 4; ++n) {
            int rb = (n * 16 + ln) * 128;
            bf16x8 v0 = *(const bf16x8*)(vb + ((rb + lg * 16) ^ swz));
            bf16x8 v1 = *(const bf16x8*)(vb + ((rb + 64 + lg * 16) ^ swz));
            o[n] = __builtin_amdgcn_mfma_f32_16x16x32_bf16(pa0, v0, o[n], 0, 0, 0);
            o[n] = __builtin_amdgcn_mfma_f32_16x16x32_bf16(pa1, v1, o[n], 0, 0, 0);
        }
        __builtin_amdgcn_s_setprio(0);

        __syncthreads();
        unsigned short* tk = kcur; kcur = knx; knx = tk;
        unsigned short* tv = vcur; vcur = vnx; vnx = tv;
    }

#pragma unroll
    for (int r = 0; r < 4; r++) {
        float Lr = __shfl(lrun, lg * 4 + r);
        float inv = 1.0f / Lr;
        int row = q0 + lg * 4 + r;
#pragma unroll
        for (int n = 0; n < 4; n++)
            out[((size_t)b * SEQ + row) * HD + n * 16 + ln] = o[n][r] * inv;
    }
}

// ---------------------------------------------------------------------------
extern "C" void kernel_launch(void* const* d_in, const int* in_sizes, int n_in,
                              void* d_out, int out_size, void* d_ws, size_t ws_size,
                              hipStream_t stream) {
    const float* x  = (const float*)d_in[0];
    const int*   am = (const int*)d_in[1];
    const float* Wq = (const float*)d_in[2];
    const float* bq = (const float*)d_in[3];
    const float* Wk = (const float*)d_in[4];
    const float* bk = (const float*)d_in[5];
    const float* Wv = (const float*)d_in[6];
    const float* bv = (const float*)d_in[7];
    float* out = (float*)d_out;

    unsigned short* ws = (unsigned short*)d_ws;
    unsigned short* Wt  = ws;
    unsigned short* Qw  = ws + 3 * HD * DMODEL;
    unsigned short* Kw  = Qw + (size_t)BATCH * SEQ * HD;
    unsigned short* VTw = Kw + (size_t)BATCH * SEQ * HD;

    prep_w<<<48, 256, 0, stream>>>(Wq, Wk, Wv, Wt);
    proj_kernel<<<(BATCH * SEQ) / 64, 256, 0, stream>>>(x, bq, bk, bv, Wt, Qw, Kw, VTw);
    attn_kernel<<<dim3(SEQ / 64, BATCH), 256, 0, stream>>>(Qw, Kw, VTw, am, out);
}

// Round 6
// 70.130 us; speedup vs baseline: 2.1088x; 1.1433x over previous
//
#include <hip/hip_runtime.h>
#include <hip/hip_bf16.h>

#define BATCH 8
#define SEQ   2048
#define DMODEL 1024
#define HD    64

typedef __attribute__((ext_vector_type(8))) short bf16x8;
typedef __attribute__((ext_vector_type(4))) float f32x4;
typedef __attribute__((ext_vector_type(2))) unsigned uint2v;
typedef unsigned int u32;

__device__ inline unsigned short f2bf(float f) {
    unsigned u = __builtin_bit_cast(unsigned, f);
    unsigned r = (u + 0x7FFFu + ((u >> 16) & 1u)) >> 16;  // RTNE
    return (unsigned short)r;
}

__device__ inline unsigned cvtpk(float lo, float hi) {
    unsigned r;
    asm("v_cvt_pk_bf16_f32 %0, %1, %2" : "=v"(r) : "v"(lo), "v"(hi));
    return r;
}

// async global->LDS, 16B per lane; LDS dest must be linear (base + lane*16)
__device__ inline void gl_lds16(const void* g, void* l) {
    __builtin_amdgcn_global_load_lds(
        (const __attribute__((address_space(1))) u32*)g,
        (__attribute__((address_space(3))) u32*)l, 16, 0, 0);
}

// ---------------------------------------------------------------------------
// Kernel 1: coalesced LDS-tiled transpose + bf16 cast of the weights.
// W[p]: [DMODEL][HD] f32 -> Wt[p]: [HD][DMODEL] bf16
// ---------------------------------------------------------------------------
__global__ void prep_w(const float* __restrict__ Wq, const float* __restrict__ Wk,
                       const float* __restrict__ Wv, unsigned short* __restrict__ Wt) {
    __shared__ float t[64][65];
    int p = blockIdx.x >> 4;
    int k0 = (blockIdx.x & 15) * 64;
    const float* W = (p == 0) ? Wq : (p == 1) ? Wk : Wv;
#pragma unroll
    for (int j = 0; j < 16; j++) {
        int idx = threadIdx.x + j * 256;
        int r = idx >> 6, c = idx & 63;
        t[r][c] = W[(size_t)(k0 + r) * HD + c];
    }
    __syncthreads();
#pragma unroll
    for (int j = 0; j < 16; j++) {
        int idx = threadIdx.x + j * 256;
        int h = idx >> 6, kk = idx & 63;
        Wt[(size_t)p * HD * DMODEL + (size_t)h * DMODEL + k0 + kk] = f2bf(t[kk][h]);
    }
}

// ---------------------------------------------------------------------------
// Kernel 2: projections. BM=32, BN=192, K_STEP=64, grid 512 (2 blocks/CU).
// x: f32 -> regs (2-deep) -> cvt_pk -> swizzled LDS (4KB, dbuf).
// W: global->reg fragments, prefetched 2 steps ahead (L2-hot, no sharing).
// Wave = 2 m-frags x 3 n-frags. Fully unrolled K-loop (static reg indexing).
// ---------------------------------------------------------------------------
__global__ __launch_bounds__(256) void proj_kernel(
    const float* __restrict__ x,
    const float* __restrict__ bq, const float* __restrict__ bk, const float* __restrict__ bv,
    const unsigned short* __restrict__ Wt,
    unsigned short* __restrict__ Q, unsigned short* __restrict__ K,
    unsigned short* __restrict__ VT) {

    __shared__ __align__(16) unsigned short Xls[2][32 * 64];  // 4KB each

    int tid = threadIdx.x;
    int w = tid >> 6, lane = tid & 63;
    int lg = lane >> 4, ln = lane & 15;
    int m0 = blockIdx.x * 32;

    // W fragment base pointers (wave's 3 n-frags, rows (w*3+j)*16+ln)
    const unsigned short* wb[3];
#pragma unroll
    for (int j = 0; j < 3; j++)
        wb[j] = Wt + (size_t)((w * 3 + j) * 16 + ln) * DMODEL + lg * 8;

    f32x4 acc[2][3];
#pragma unroll
    for (int m = 0; m < 2; m++)
#pragma unroll
        for (int j = 0; j < 3; j++) acc[m][j] = (f32x4){0.f, 0.f, 0.f, 0.f};

    // x staging: thread covers 2 chunks c = tid + i*256; row=c>>4, colf=(c&15)*4
    f32x4 xq[2][2];
    bf16x8 bset[2][6];

    auto loadX = [&](int set, int k0) {
#pragma unroll
        for (int i = 0; i < 2; i++) {
            int c = tid + i * 256;
            xq[set][i] = *(const f32x4*)(x + (size_t)(m0 + (c >> 4)) * DMODEL + k0 + (c & 15) * 4);
        }
    };
    auto writeX = [&](unsigned short* buf, int set) {
#pragma unroll
        for (int i = 0; i < 2; i++) {
            int c = tid + i * 256;
            int row = c >> 4, slot = (c & 15) >> 1, half = c & 1;
            uint2v pk;
            pk[0] = cvtpk(xq[set][i][0], xq[set][i][1]);
            pk[1] = cvtpk(xq[set][i][2], xq[set][i][3]);
            *(uint2v*)((char*)buf + row * 128 + ((slot ^ (row & 7)) << 4) + half * 8) = pk;
        }
    };
    auto loadB = [&](int set, int k0) {
#pragma unroll
        for (int s = 0; s < 2; s++)
#pragma unroll
            for (int j = 0; j < 3; j++)
                bset[set][s * 3 + j] = *(const bf16x8*)(wb[j] + k0 + s * 32);
    };

    // prologue: step0 staged; x 2-deep; W 2-deep
    loadX(0, 0);
    writeX(&Xls[0][0], 0);
    loadX(1, 64);
    loadX(0, 128);
    loadB(0, 0);
    loadB(1, 64);
    __syncthreads();

#pragma unroll
    for (int t = 0; t < 16; t++) {
        const int cur = t & 1;
        const char* xb = (const char*)&Xls[cur][0];

#pragma unroll
        for (int s = 0; s < 2; s++) {
            bf16x8 a[2];
#pragma unroll
            for (int m = 0; m < 2; m++) {
                int row = m * 16 + ln;
                a[m] = *(const bf16x8*)(xb + row * 128 + (((s * 4 + lg) ^ (row & 7)) << 4));
            }
            __builtin_amdgcn_s_setprio(1);
#pragma unroll
            for (int m = 0; m < 2; m++)
#pragma unroll
                for (int j = 0; j < 3; j++)
                    acc[m][j] = __builtin_amdgcn_mfma_f32_16x16x32_bf16(a[m], bset[cur][s * 3 + j], acc[m][j], 0, 0, 0);
            __builtin_amdgcn_s_setprio(0);
        }

        if (t + 2 < 16) loadB(cur, (t + 2) * 64);          // W prefetch 2 ahead
        if (t < 15) {
            writeX(&Xls[cur ^ 1][0], (t + 1) & 1);         // stage x for t+1
            if (t + 3 < 16) loadX((t + 1) & 1, (t + 3) * 64);
        }
        __syncthreads();
    }

    // epilogue: wave owns 3 n-frags over 32 m-rows
#pragma unroll
    for (int j = 0; j < 3; j++) {
        int f = w * 3 + j;
        int p = f >> 2, n = f & 3;
        int col = n * 16 + ln;
        const float* bias = (p == 0) ? bq : (p == 1) ? bk : bv;
        float bb = bias[col];
#pragma unroll
        for (int m = 0; m < 2; m++) {
#pragma unroll
            for (int r = 0; r < 4; r++) {
                float v = acc[m][j][r] + bb;
                int grow = m0 + m * 16 + lg * 4 + r;
                if (p == 0)      Q[(size_t)grow * HD + col] = f2bf(v);
                else if (p == 1) K[(size_t)grow * HD + col] = f2bf(v);
                else {
                    int b2 = grow >> 11, srow = grow & (SEQ - 1);
                    VT[((size_t)b2 * HD + col) * SEQ + srow] = f2bf(v);
                }
            }
        }
    }
}

// ---------------------------------------------------------------------------
// Kernel 3: flash attention, keys split across gridDim.z blocks.
// Block = 64 q-rows (4 waves x 16); K/V staged via global_load_lds (swizzled
// source), dbuf; swapped-QK^T in-lane softmax; partials to ws when split.
// ---------------------------------------------------------------------------
__device__ inline void stage_tile(int tid, const unsigned short* Kb, const unsigned short* VTb,
                                  int kt, unsigned short* kbuf, unsigned short* vbuf) {
#pragma unroll
    for (int i = 0; i < 2; i++) {
        int d = tid * 16 + i * 4096;
        int row = d >> 7, slot = (d >> 4) & 7;
        const unsigned short* src = Kb + (size_t)(kt + row) * HD + ((slot ^ (row & 7)) << 3);
        gl_lds16(src, (char*)kbuf + d);
    }
#pragma unroll
    for (int i = 0; i < 2; i++) {
        int d = tid * 16 + i * 4096;
        int row = d >> 7, slot = (d >> 4) & 7;
        const unsigned short* src = VTb + (size_t)row * SEQ + kt + ((slot ^ (row & 7)) << 3);
        gl_lds16(src, (char*)vbuf + d);
    }
}

__global__ __launch_bounds__(256, 2) void attn_kernel(
    const unsigned short* __restrict__ Q, const unsigned short* __restrict__ K,
    const unsigned short* __restrict__ VT, const int* __restrict__ mask,
    float* __restrict__ out,
    float* __restrict__ Op, float* __restrict__ Mp, float* __restrict__ Lp,
    int nsplit) {

    __shared__ __align__(16) unsigned short Kls[2][64 * 64];
    __shared__ __align__(16) unsigned short Vls[2][64 * 64];
    __shared__ __align__(16) unsigned short plds_[4][16 * 64];
    __shared__ float biasl[SEQ];

    int tid = threadIdx.x;
    int w = tid >> 6, lane = tid & 63;
    int lg = lane >> 4, ln = lane & 15;
    int b = blockIdx.y;
    int kh = blockIdx.z;
    int q0 = blockIdx.x * 64 + w * 16;
    int ntiles = 32 / nsplit;
    int kt0 = kh * ntiles * 64;

    const float SC = 0.125f * 1.44269504088896f;

    const int* mb = mask + b * SEQ;
    for (int i = tid; i < SEQ; i += 256)
        biasl[i] = mb[i] ? 0.f : -1e30f;

    bf16x8 qf[2];
    {
        const unsigned short* qptr = Q + ((size_t)b * SEQ + q0 + ln) * HD + lg * 8;
        qf[0] = *(const bf16x8*)(qptr);
        qf[1] = *(const bf16x8*)(qptr + 32);
    }

    f32x4 o[4];
#pragma unroll
    for (int n = 0; n < 4; n++) o[n] = (f32x4){0.f, 0.f, 0.f, 0.f};
    float mrun = -1e38f, lrun = 0.f;

    const unsigned short* Kb = K + (size_t)b * SEQ * HD;
    const unsigned short* VTb = VT + (size_t)b * HD * SEQ;

    unsigned short* kcur = &Kls[0][0]; unsigned short* knx = &Kls[1][0];
    unsigned short* vcur = &Vls[0][0]; unsigned short* vnx = &Vls[1][0];
    char* pl = (char*)&plds_[w][0];
    const int swz = (ln & 7) << 4;

    stage_tile(tid, Kb, VTb, kt0, kcur, vcur);
    __syncthreads();

#pragma unroll 2
    for (int tt = 0; tt < ntiles; ++tt) {
        int kt = kt0 + tt * 64;
        if (tt < ntiles - 1) stage_tile(tid, Kb, VTb, kt + 64, knx, vnx);

        f32x4 st[4];
        const char* kb = (const char*)kcur;
        __builtin_amdgcn_s_setprio(1);
#pragma unroll
        for (int n = 0; n < 4; ++n) {
            int rb = (n * 16 + ln) * 128;
            bf16x8 ka0 = *(const bf16x8*)(kb + ((rb + lg * 16) ^ swz));
            bf16x8 ka1 = *(const bf16x8*)(kb + ((rb + 64 + lg * 16) ^ swz));
            f32x4 z = (f32x4){0.f, 0.f, 0.f, 0.f};
            st[n] = __builtin_amdgcn_mfma_f32_16x16x32_bf16(ka0, qf[0], z, 0, 0, 0);
            st[n] = __builtin_amdgcn_mfma_f32_16x16x32_bf16(ka1, qf[1], st[n], 0, 0, 0);
        }
        __builtin_amdgcn_s_setprio(0);

#pragma unroll
        for (int n = 0; n < 4; ++n) {
            f32x4 bv4 = *(const f32x4*)&biasl[kt + n * 16 + lg * 4];
#pragma unroll
            for (int r = 0; r < 4; ++r)
                st[n][r] = fmaf(st[n][r], SC, bv4[r]);
        }

        f32x4 mx = st[0];
#pragma unroll
        for (int n = 1; n < 4; ++n)
#pragma unroll
            for (int r = 0; r < 4; ++r) mx[r] = fmaxf(mx[r], st[n][r]);
        float pmax = fmaxf(fmaxf(mx[0], mx[1]), fmaxf(mx[2], mx[3]));
        pmax = fmaxf(pmax, __shfl_xor(pmax, 16));
        pmax = fmaxf(pmax, __shfl_xor(pmax, 32));

        if (!__all(pmax <= mrun + 8.f)) {
            float mnew = fmaxf(mrun, pmax);
            float corr = exp2f(mrun - mnew);
            mrun = mnew;
            lrun *= corr;
            float c0 = __shfl(corr, lg * 4 + 0);
            float c1 = __shfl(corr, lg * 4 + 1);
            float c2 = __shfl(corr, lg * 4 + 2);
            float c3 = __shfl(corr, lg * 4 + 3);
#pragma unroll
            for (int n = 0; n < 4; ++n) {
                o[n][0] *= c0; o[n][1] *= c1; o[n][2] *= c2; o[n][3] *= c3;
            }
        }

        f32x4 sv = (f32x4){0.f, 0.f, 0.f, 0.f};
#pragma unroll
        for (int n = 0; n < 4; ++n)
#pragma unroll
            for (int r = 0; r < 4; ++r) {
                float pp = exp2f(st[n][r] - mrun);
                st[n][r] = pp;
                sv[r] += pp;
            }
        float ts = (sv[0] + sv[1]) + (sv[2] + sv[3]);
        ts += __shfl_xor(ts, 16);
        ts += __shfl_xor(ts, 32);
        lrun += ts;

#pragma unroll
        for (int n = 0; n < 4; ++n) {
            uint2v ww;
            ww[0] = cvtpk(st[n][0], st[n][1]);
            ww[1] = cvtpk(st[n][2], st[n][3]);
            *(uint2v*)(pl + ((ln * 128 + n * 32 + lg * 8) ^ swz)) = ww;
        }
        asm volatile("s_waitcnt lgkmcnt(0)" ::: "memory");
        __builtin_amdgcn_sched_barrier(0);
        bf16x8 pa0 = *(const bf16x8*)(pl + ((ln * 128 + lg * 16) ^ swz));
        bf16x8 pa1 = *(const bf16x8*)(pl + ((ln * 128 + 64 + lg * 16) ^ swz));

        const char* vb = (const char*)vcur;
        __builtin_amdgcn_s_setprio(1);
#pragma unroll
        for (int n = 0; n < 4; ++n) {
            int rb = (n * 16 + ln) * 128;
            bf16x8 v0 = *(const bf16x8*)(vb + ((rb + lg * 16) ^ swz));
            bf16x8 v1 = *(const bf16x8*)(vb + ((rb + 64 + lg * 16) ^ swz));
            o[n] = __builtin_amdgcn_mfma_f32_16x16x32_bf16(pa0, v0, o[n], 0, 0, 0);
            o[n] = __builtin_amdgcn_mfma_f32_16x16x32_bf16(pa1, v1, o[n], 0, 0, 0);
        }
        __builtin_amdgcn_s_setprio(0);

        __syncthreads();
        unsigned short* tk = kcur; kcur = knx; knx = tk;
        unsigned short* tv = vcur; vcur = vnx; vnx = tv;
    }

    if (nsplit == 1) {
#pragma unroll
        for (int r = 0; r < 4; r++) {
            float Lr = __shfl(lrun, lg * 4 + r);
            float inv = 1.0f / Lr;
            int row = q0 + lg * 4 + r;
#pragma unroll
            for (int n = 0; n < 4; n++)
                out[((size_t)b * SEQ + row) * HD + n * 16 + ln] = o[n][r] * inv;
        }
    } else {
        // unnormalized O + (m, l) partials
        size_t base = (size_t)kh * BATCH * SEQ * HD;
#pragma unroll
        for (int r = 0; r < 4; r++) {
            int row = q0 + lg * 4 + r;
            size_t gr = (size_t)b * SEQ + row;
#pragma unroll
            for (int n = 0; n < 4; n++)
                Op[base + gr * HD + n * 16 + ln] = o[n][r];
        }
        if (lane < 16) {
            size_t gr = (size_t)b * SEQ + q0 + ln;
            Mp[(size_t)kh * BATCH * SEQ + gr] = mrun;
            Lp[(size_t)kh * BATCH * SEQ + gr] = lrun;
        }
    }
}

// ---------------------------------------------------------------------------
// Kernel 4: combine 2 key-split partials -> out
// ---------------------------------------------------------------------------
__global__ __launch_bounds__(256) void combine_kernel(
    const float* __restrict__ Op, const float* __restrict__ Mp,
    const float* __restrict__ Lp, float* __restrict__ out) {
    int g = blockIdx.x * 256 + threadIdx.x;     // 262144 threads, f32x4 each
    int row = g >> 4;
    int c4 = (g & 15) << 2;
    const int NR = BATCH * SEQ;
    float m0 = Mp[row], m1 = Mp[NR + row];
    float l0 = Lp[row], l1 = Lp[NR + row];
    float M = fmaxf(m0, m1);
    float e0 = exp2f(m0 - M), e1 = exp2f(m1 - M);
    float inv = 1.0f / (l0 * e0 + l1 * e1);
    f32x4 o0 = *(const f32x4*)(Op + (size_t)row * HD + c4);
    f32x4 o1 = *(const f32x4*)(Op + (size_t)NR * HD + (size_t)row * HD + c4);
    f32x4 r;
#pragma unroll
    for (int i = 0; i < 4; i++) r[i] = (o0[i] * e0 + o1[i] * e1) * inv;
    *(f32x4*)(out + (size_t)row * HD + c4) = r;
}

// ---------------------------------------------------------------------------
extern "C" void kernel_launch(void* const* d_in, const int* in_sizes, int n_in,
                              void* d_out, int out_size, void* d_ws, size_t ws_size,
                              hipStream_t stream) {
    const float* x  = (const float*)d_in[0];
    const int*   am = (const int*)d_in[1];
    const float* Wq = (const float*)d_in[2];
    const float* bq = (const float*)d_in[3];
    const float* Wk = (const float*)d_in[4];
    const float* bk = (const float*)d_in[5];
    const float* Wv = (const float*)d_in[6];
    const float* bv = (const float*)d_in[7];
    float* out = (float*)d_out;

    unsigned short* ws = (unsigned short*)d_ws;
    unsigned short* Wt  = ws;                               // 196608 sh
    unsigned short* Qw  = ws + 3 * HD * DMODEL;
    unsigned short* Kw  = Qw + (size_t)BATCH * SEQ * HD;
    unsigned short* VTw = Kw + (size_t)BATCH * SEQ * HD;
    size_t base_sh = 3 * HD * DMODEL + 3 * (size_t)BATCH * SEQ * HD;   // shorts used
    float* Op = (float*)(ws + base_sh);                     // [2][B*S][HD] f32
    float* Mp = Op + 2 * (size_t)BATCH * SEQ * HD;          // [2][B*S]
    float* Lp = Mp + 2 * (size_t)BATCH * SEQ;               // [2][B*S]
    size_t need = base_sh * 2 + (2 * (size_t)BATCH * SEQ * HD + 4 * (size_t)BATCH * SEQ) * 4;

    int nsplit = (ws_size >= need) ? 2 : 1;

    prep_w<<<48, 256, 0, stream>>>(Wq, Wk, Wv, Wt);
    proj_kernel<<<(BATCH * SEQ) / 32, 256, 0, stream>>>(x, bq, bk, bv, Wt, Qw, Kw, VTw);
    attn_kernel<<<dim3(SEQ / 64, BATCH, nsplit), 256, 0, stream>>>(Qw, Kw, VTw, am, out,
                                                                   Op, Mp, Lp, nsplit);
    if (nsplit == 2)
        combine_kernel<<<(BATCH * SEQ * HD / 4) / 256, 256, 0, stream>>>(Op, Mp, Lp, out);
}

// Round 7
// 65.407 us; speedup vs baseline: 2.2611x; 1.0722x over previous
//
#include <hip/hip_runtime.h>
#include <hip/hip_bf16.h>

#define BATCH 8
#define SEQ   2048
#define DMODEL 1024
#define HD    64

typedef __attribute__((ext_vector_type(8))) short bf16x8;
typedef __attribute__((ext_vector_type(4))) float f32x4;
typedef __attribute__((ext_vector_type(4))) int int4v;
typedef __attribute__((ext_vector_type(2))) unsigned uint2v;
typedef unsigned int u32;

__device__ inline unsigned short f2bf(float f) {
    unsigned u = __builtin_bit_cast(unsigned, f);
    unsigned r = (u + 0x7FFFu + ((u >> 16) & 1u)) >> 16;  // RTNE
    return (unsigned short)r;
}

__device__ inline unsigned cvtpk(float lo, float hi) {
    unsigned r;
    asm("v_cvt_pk_bf16_f32 %0, %1, %2" : "=v"(r) : "v"(lo), "v"(hi));
    return r;
}

// async global->LDS, 16B per lane; LDS dest must be linear (base + lane*16)
__device__ inline void gl_lds16(const void* g, void* l) {
    __builtin_amdgcn_global_load_lds(
        (const __attribute__((address_space(1))) u32*)g,
        (__attribute__((address_space(3))) u32*)l, 16, 0, 0);
}

// ---------------------------------------------------------------------------
// Kernel 1: coalesced LDS-tiled transpose + bf16 cast of the weights.
// ---------------------------------------------------------------------------
__global__ void prep_w(const float* __restrict__ Wq, const float* __restrict__ Wk,
                       const float* __restrict__ Wv, unsigned short* __restrict__ Wt) {
    __shared__ float t[64][65];
    int p = blockIdx.x >> 4;
    int k0 = (blockIdx.x & 15) * 64;
    const float* W = (p == 0) ? Wq : (p == 1) ? Wk : Wv;
#pragma unroll
    for (int j = 0; j < 16; j++) {
        int idx = threadIdx.x + j * 256;
        int r = idx >> 6, c = idx & 63;
        t[r][c] = W[(size_t)(k0 + r) * HD + c];
    }
    __syncthreads();
#pragma unroll
    for (int j = 0; j < 16; j++) {
        int idx = threadIdx.x + j * 256;
        int h = idx >> 6, kk = idx & 63;
        Wt[(size_t)p * HD * DMODEL + (size_t)h * DMODEL + k0 + kk] = f2bf(t[kk][h]);
    }
}

// ---------------------------------------------------------------------------
// Kernel 2: projections. BM=32, BN=192, K_STEP=64, grid 512 (2 blocks/CU).
// (unchanged from R6)
// ---------------------------------------------------------------------------
__global__ __launch_bounds__(256) void proj_kernel(
    const float* __restrict__ x,
    const float* __restrict__ bq, const float* __restrict__ bk, const float* __restrict__ bv,
    const unsigned short* __restrict__ Wt,
    unsigned short* __restrict__ Q, unsigned short* __restrict__ K,
    unsigned short* __restrict__ VT) {

    __shared__ __align__(16) unsigned short Xls[2][32 * 64];

    int tid = threadIdx.x;
    int w = tid >> 6, lane = tid & 63;
    int lg = lane >> 4, ln = lane & 15;
    int m0 = blockIdx.x * 32;

    const unsigned short* wb[3];
#pragma unroll
    for (int j = 0; j < 3; j++)
        wb[j] = Wt + (size_t)((w * 3 + j) * 16 + ln) * DMODEL + lg * 8;

    f32x4 acc[2][3];
#pragma unroll
    for (int m = 0; m < 2; m++)
#pragma unroll
        for (int j = 0; j < 3; j++) acc[m][j] = (f32x4){0.f, 0.f, 0.f, 0.f};

    f32x4 xq[2][2];
    bf16x8 bset[2][6];

    auto loadX = [&](int set, int k0) {
#pragma unroll
        for (int i = 0; i < 2; i++) {
            int c = tid + i * 256;
            xq[set][i] = *(const f32x4*)(x + (size_t)(m0 + (c >> 4)) * DMODEL + k0 + (c & 15) * 4);
        }
    };
    auto writeX = [&](unsigned short* buf, int set) {
#pragma unroll
        for (int i = 0; i < 2; i++) {
            int c = tid + i * 256;
            int row = c >> 4, slot = (c & 15) >> 1, half = c & 1;
            uint2v pk;
            pk[0] = cvtpk(xq[set][i][0], xq[set][i][1]);
            pk[1] = cvtpk(xq[set][i][2], xq[set][i][3]);
            *(uint2v*)((char*)buf + row * 128 + ((slot ^ (row & 7)) << 4) + half * 8) = pk;
        }
    };
    auto loadB = [&](int set, int k0) {
#pragma unroll
        for (int s = 0; s < 2; s++)
#pragma unroll
            for (int j = 0; j < 3; j++)
                bset[set][s * 3 + j] = *(const bf16x8*)(wb[j] + k0 + s * 32);
    };

    loadX(0, 0);
    writeX(&Xls[0][0], 0);
    loadX(1, 64);
    loadX(0, 128);
    loadB(0, 0);
    loadB(1, 64);
    __syncthreads();

#pragma unroll
    for (int t = 0; t < 16; t++) {
        const int cur = t & 1;
        const char* xb = (const char*)&Xls[cur][0];

#pragma unroll
        for (int s = 0; s < 2; s++) {
            bf16x8 a[2];
#pragma unroll
            for (int m = 0; m < 2; m++) {
                int row = m * 16 + ln;
                a[m] = *(const bf16x8*)(xb + row * 128 + (((s * 4 + lg) ^ (row & 7)) << 4));
            }
            __builtin_amdgcn_s_setprio(1);
#pragma unroll
            for (int m = 0; m < 2; m++)
#pragma unroll
                for (int j = 0; j < 3; j++)
                    acc[m][j] = __builtin_amdgcn_mfma_f32_16x16x32_bf16(a[m], bset[cur][s * 3 + j], acc[m][j], 0, 0, 0);
            __builtin_amdgcn_s_setprio(0);
        }

        if (t + 2 < 16) loadB(cur, (t + 2) * 64);
        if (t < 15) {
            writeX(&Xls[cur ^ 1][0], (t + 1) & 1);
            if (t + 3 < 16) loadX((t + 1) & 1, (t + 3) * 64);
        }
        __syncthreads();
    }

#pragma unroll
    for (int j = 0; j < 3; j++) {
        int f = w * 3 + j;
        int p = f >> 2, n = f & 3;
        int col = n * 16 + ln;
        const float* bias = (p == 0) ? bq : (p == 1) ? bk : bv;
        float bb = bias[col];
#pragma unroll
        for (int m = 0; m < 2; m++) {
#pragma unroll
            for (int r = 0; r < 4; r++) {
                float v = acc[m][j][r] + bb;
                int grow = m0 + m * 16 + lg * 4 + r;
                if (p == 0)      Q[(size_t)grow * HD + col] = f2bf(v);
                else if (p == 1) K[(size_t)grow * HD + col] = f2bf(v);
                else {
                    int b2 = grow >> 11, srow = grow & (SEQ - 1);
                    VT[((size_t)b2 * HD + col) * SEQ + srow] = f2bf(v);
                }
            }
        }
    }
}

// ---------------------------------------------------------------------------
// Kernel 3: flash attention, keys split 4x across blocks. 40KB LDS ->
// 4 blocks/CU. Mask loaded per-tile as int4 from global (no LDS bias).
// Partials (bf16 O, f32 m/l) to workspace.
// ---------------------------------------------------------------------------
__device__ inline void stage_tile(int tid, const unsigned short* Kb, const unsigned short* VTb,
                                  int kt, unsigned short* kbuf, unsigned short* vbuf) {
#pragma unroll
    for (int i = 0; i < 2; i++) {
        int d = tid * 16 + i * 4096;
        int row = d >> 7, slot = (d >> 4) & 7;
        const unsigned short* src = Kb + (size_t)(kt + row) * HD + ((slot ^ (row & 7)) << 3);
        gl_lds16(src, (char*)kbuf + d);
    }
#pragma unroll
    for (int i = 0; i < 2; i++) {
        int d = tid * 16 + i * 4096;
        int row = d >> 7, slot = (d >> 4) & 7;
        const unsigned short* src = VTb + (size_t)row * SEQ + kt + ((slot ^ (row & 7)) << 3);
        gl_lds16(src, (char*)vbuf + d);
    }
}

__global__ __launch_bounds__(256, 4) void attn_kernel(
    const unsigned short* __restrict__ Q, const unsigned short* __restrict__ K,
    const unsigned short* __restrict__ VT, const int* __restrict__ mask,
    float* __restrict__ out,
    unsigned short* __restrict__ Op, float* __restrict__ Mp, float* __restrict__ Lp,
    int nsplit) {

    __shared__ __align__(16) unsigned short Kls[2][64 * 64];   // 16KB
    __shared__ __align__(16) unsigned short Vls[2][64 * 64];   // 16KB
    __shared__ __align__(16) unsigned short plds_[4][16 * 64]; // 8KB

    int tid = threadIdx.x;
    int w = tid >> 6, lane = tid & 63;
    int lg = lane >> 4, ln = lane & 15;
    int b = blockIdx.y;
    int kh = blockIdx.z;
    int q0 = blockIdx.x * 64 + w * 16;
    int ntiles = 32 / nsplit;
    int kt0 = kh * ntiles * 64;

    const float SC = 0.125f * 1.44269504088896f;

    const int* mb = mask + b * SEQ;

    bf16x8 qf[2];
    {
        const unsigned short* qptr = Q + ((size_t)b * SEQ + q0 + ln) * HD + lg * 8;
        qf[0] = *(const bf16x8*)(qptr);
        qf[1] = *(const bf16x8*)(qptr + 32);
    }

    f32x4 o[4];
#pragma unroll
    for (int n = 0; n < 4; n++) o[n] = (f32x4){0.f, 0.f, 0.f, 0.f};
    float mrun = -1e38f, lrun = 0.f;

    const unsigned short* Kb = K + (size_t)b * SEQ * HD;
    const unsigned short* VTb = VT + (size_t)b * HD * SEQ;

    unsigned short* kcur = &Kls[0][0]; unsigned short* knx = &Kls[1][0];
    unsigned short* vcur = &Vls[0][0]; unsigned short* vnx = &Vls[1][0];
    char* pl = (char*)&plds_[w][0];
    const int swz = (ln & 7) << 4;

    stage_tile(tid, Kb, VTb, kt0, kcur, vcur);
    __syncthreads();

#pragma unroll 2
    for (int tt = 0; tt < ntiles; ++tt) {
        int kt = kt0 + tt * 64;
        if (tt < ntiles - 1) stage_tile(tid, Kb, VTb, kt + 64, knx, vnx);

        // mask int4 for this tile (L1-hot, hoistable)
        int4v mi[4];
#pragma unroll
        for (int n = 0; n < 4; ++n)
            mi[n] = *(const int4v*)(mb + kt + n * 16 + lg * 4);

        f32x4 st[4];
        const char* kb = (const char*)kcur;
        __builtin_amdgcn_s_setprio(1);
#pragma unroll
        for (int n = 0; n < 4; ++n) {
            int rb = (n * 16 + ln) * 128;
            bf16x8 ka0 = *(const bf16x8*)(kb + ((rb + lg * 16) ^ swz));
            bf16x8 ka1 = *(const bf16x8*)(kb + ((rb + 64 + lg * 16) ^ swz));
            f32x4 z = (f32x4){0.f, 0.f, 0.f, 0.f};
            st[n] = __builtin_amdgcn_mfma_f32_16x16x32_bf16(ka0, qf[0], z, 0, 0, 0);
            st[n] = __builtin_amdgcn_mfma_f32_16x16x32_bf16(ka1, qf[1], st[n], 0, 0, 0);
        }
        __builtin_amdgcn_s_setprio(0);

#pragma unroll
        for (int n = 0; n < 4; ++n)
#pragma unroll
            for (int r = 0; r < 4; ++r)
                st[n][r] = fmaf(st[n][r], SC, mi[n][r] ? 0.f : -1e30f);

        f32x4 mx = st[0];
#pragma unroll
        for (int n = 1; n < 4; ++n)
#pragma unroll
            for (int r = 0; r < 4; ++r) mx[r] = fmaxf(mx[r], st[n][r]);
        float pmax = fmaxf(fmaxf(mx[0], mx[1]), fmaxf(mx[2], mx[3]));
        pmax = fmaxf(pmax, __shfl_xor(pmax, 16));
        pmax = fmaxf(pmax, __shfl_xor(pmax, 32));

        if (!__all(pmax <= mrun + 8.f)) {
            float mnew = fmaxf(mrun, pmax);
            float corr = exp2f(mrun - mnew);
            mrun = mnew;
            lrun *= corr;
            float c0 = __shfl(corr, lg * 4 + 0);
            float c1 = __shfl(corr, lg * 4 + 1);
            float c2 = __shfl(corr, lg * 4 + 2);
            float c3 = __shfl(corr, lg * 4 + 3);
#pragma unroll
            for (int n = 0; n < 4; ++n) {
                o[n][0] *= c0; o[n][1] *= c1; o[n][2] *= c2; o[n][3] *= c3;
            }
        }

        f32x4 sv = (f32x4){0.f, 0.f, 0.f, 0.f};
#pragma unroll
        for (int n = 0; n < 4; ++n)
#pragma unroll
            for (int r = 0; r < 4; ++r) {
                float pp = exp2f(st[n][r] - mrun);
                st[n][r] = pp;
                sv[r] += pp;
            }
        float ts = (sv[0] + sv[1]) + (sv[2] + sv[3]);
        ts += __shfl_xor(ts, 16);
        ts += __shfl_xor(ts, 32);
        lrun += ts;

#pragma unroll
        for (int n = 0; n < 4; ++n) {
            uint2v ww;
            ww[0] = cvtpk(st[n][0], st[n][1]);
            ww[1] = cvtpk(st[n][2], st[n][3]);
            *(uint2v*)(pl + ((ln * 128 + n * 32 + lg * 8) ^ swz)) = ww;
        }
        asm volatile("s_waitcnt lgkmcnt(0)" ::: "memory");
        __builtin_amdgcn_sched_barrier(0);
        bf16x8 pa0 = *(const bf16x8*)(pl + ((ln * 128 + lg * 16) ^ swz));
        bf16x8 pa1 = *(const bf16x8*)(pl + ((ln * 128 + 64 + lg * 16) ^ swz));

        const char* vb = (const char*)vcur;
        __builtin_amdgcn_s_setprio(1);
#pragma unroll
        for (int n = 0; n < 4; ++n) {
            int rb = (n * 16 + ln) * 128;
            bf16x8 v0 = *(const bf16x8*)(vb + ((rb + lg * 16) ^ swz));
            bf16x8 v1 = *(const bf16x8*)(vb + ((rb + 64 + lg * 16) ^ swz));
            o[n] = __builtin_amdgcn_mfma_f32_16x16x32_bf16(pa0, v0, o[n], 0, 0, 0);
            o[n] = __builtin_amdgcn_mfma_f32_16x16x32_bf16(pa1, v1, o[n], 0, 0, 0);
        }
        __builtin_amdgcn_s_setprio(0);

        __syncthreads();
        unsigned short* tk = kcur; kcur = knx; knx = tk;
        unsigned short* tv = vcur; vcur = vnx; vnx = tv;
    }

    if (nsplit == 1) {
#pragma unroll
        for (int r = 0; r < 4; r++) {
            float Lr = __shfl(lrun, lg * 4 + r);
            float inv = 1.0f / Lr;
            int row = q0 + lg * 4 + r;
#pragma unroll
            for (int n = 0; n < 4; n++)
                out[((size_t)b * SEQ + row) * HD + n * 16 + ln] = o[n][r] * inv;
        }
    } else {
        // unnormalized O (bf16) + (m, l) partials
        size_t base = (size_t)kh * BATCH * SEQ * HD;
#pragma unroll
        for (int r = 0; r < 4; r++) {
            int row = q0 + lg * 4 + r;
            size_t gr = (size_t)b * SEQ + row;
#pragma unroll
            for (int n = 0; n < 4; n++)
                Op[base + gr * HD + n * 16 + ln] = f2bf(o[n][r]);
        }
        if (lane < 16) {
            size_t gr = (size_t)b * SEQ + q0 + ln;
            Mp[(size_t)kh * BATCH * SEQ + gr] = mrun;
            Lp[(size_t)kh * BATCH * SEQ + gr] = lrun;
        }
    }
}

// ---------------------------------------------------------------------------
// Kernel 4: combine 4 key-split partials -> out. Thread = 8 cols of one row.
// ---------------------------------------------------------------------------
__global__ __launch_bounds__(256) void combine_kernel(
    const unsigned short* __restrict__ Op, const float* __restrict__ Mp,
    const float* __restrict__ Lp, float* __restrict__ out) {
    int g = blockIdx.x * 256 + threadIdx.x;     // B*S*8 threads
    int row = g >> 3;
    int c0 = (g & 7) * 8;
    const int NR = BATCH * SEQ;

    float m[4], l[4];
#pragma unroll
    for (int s = 0; s < 4; s++) {
        m[s] = Mp[(size_t)s * NR + row];
        l[s] = Lp[(size_t)s * NR + row];
    }
    float M = fmaxf(fmaxf(m[0], m[1]), fmaxf(m[2], m[3]));
    float e[4], L = 0.f;
#pragma unroll
    for (int s = 0; s < 4; s++) { e[s] = exp2f(m[s] - M); L += l[s] * e[s]; }
    float inv = 1.0f / L;

    float acc[8] = {0.f, 0.f, 0.f, 0.f, 0.f, 0.f, 0.f, 0.f};
#pragma unroll
    for (int s = 0; s < 4; s++) {
        bf16x8 ov = *(const bf16x8*)(Op + ((size_t)s * NR + row) * HD + c0);
#pragma unroll
        for (int i = 0; i < 8; i++) {
            float f = __builtin_bit_cast(float, ((u32)(unsigned short)ov[i]) << 16);
            acc[i] += f * e[s];
        }
    }
    f32x4 r0, r1;
#pragma unroll
    for (int i = 0; i < 4; i++) { r0[i] = acc[i] * inv; r1[i] = acc[4 + i] * inv; }
    *(f32x4*)(out + (size_t)row * HD + c0) = r0;
    *(f32x4*)(out + (size_t)row * HD + c0 + 4) = r1;
}

// ---------------------------------------------------------------------------
extern "C" void kernel_launch(void* const* d_in, const int* in_sizes, int n_in,
                              void* d_out, int out_size, void* d_ws, size_t ws_size,
                              hipStream_t stream) {
    const float* x  = (const float*)d_in[0];
    const int*   am = (const int*)d_in[1];
    const float* Wq = (const float*)d_in[2];
    const float* bq = (const float*)d_in[3];
    const float* Wk = (const float*)d_in[4];
    const float* bk = (const float*)d_in[5];
    const float* Wv = (const float*)d_in[6];
    const float* bv = (const float*)d_in[7];
    float* out = (float*)d_out;

    unsigned short* ws = (unsigned short*)d_ws;
    unsigned short* Wt  = ws;
    unsigned short* Qw  = ws + 3 * HD * DMODEL;
    unsigned short* Kw  = Qw + (size_t)BATCH * SEQ * HD;
    unsigned short* VTw = Kw + (size_t)BATCH * SEQ * HD;
    size_t base_sh = 3 * HD * DMODEL + 3 * (size_t)BATCH * SEQ * HD;
    unsigned short* Op = ws + base_sh;                      // [4][B*S][HD] bf16
    float* Mp = (float*)(Op + 4 * (size_t)BATCH * SEQ * HD);// [4][B*S]
    float* Lp = Mp + 4 * (size_t)BATCH * SEQ;               // [4][B*S]
    size_t need = base_sh * 2 + 4 * (size_t)BATCH * SEQ * HD * 2
                + 8 * (size_t)BATCH * SEQ * 4;

    int nsplit = (ws_size >= need) ? 4 : 1;

    prep_w<<<48, 256, 0, stream>>>(Wq, Wk, Wv, Wt);
    proj_kernel<<<(BATCH * SEQ) / 32, 256, 0, stream>>>(x, bq, bk, bv, Wt, Qw, Kw, VTw);
    attn_kernel<<<dim3(SEQ / 64, BATCH, nsplit), 256, 0, stream>>>(Qw, Kw, VTw, am, out,
                                                                   Op, Mp, Lp, nsplit);
    if (nsplit == 4)
        combine_kernel<<<(BATCH * SEQ * 8) / 256, 256, 0, stream>>>(Op, Mp, Lp, out);
}

// Round 8
// 55.625 us; speedup vs baseline: 2.6587x; 1.1758x over previous
//
#include <hip/hip_runtime.h>
#include <hip/hip_bf16.h>

#define BATCH 8
#define SEQ   2048
#define DMODEL 1024
#define HD    64

typedef __attribute__((ext_vector_type(8))) short bf16x8;
typedef __attribute__((ext_vector_type(4))) float f32x4;
typedef __attribute__((ext_vector_type(4))) int int4v;
typedef __attribute__((ext_vector_type(2))) unsigned uint2v;
typedef unsigned int u32;

__device__ inline unsigned short f2bf(float f) {
    unsigned u = __builtin_bit_cast(unsigned, f);
    unsigned r = (u + 0x7FFFu + ((u >> 16) & 1u)) >> 16;  // RTNE
    return (unsigned short)r;
}

__device__ inline unsigned cvtpk(float lo, float hi) {
    unsigned r;
    asm("v_cvt_pk_bf16_f32 %0, %1, %2" : "=v"(r) : "v"(lo), "v"(hi));
    return r;
}

// async global->LDS, 16B per lane; LDS dest must be linear (base + lane*16)
__device__ inline void gl_lds16(const void* g, void* l) {
    __builtin_amdgcn_global_load_lds(
        (const __attribute__((address_space(1))) u32*)g,
        (__attribute__((address_space(3))) u32*)l, 16, 0, 0);
}

// ---------------------------------------------------------------------------
// Kernel 1: weights -> fragment-major bf16 layout.
// WFrag[f][t][s][lg][ln][e] (f=p*4+n, t=k/64, s=(k/32)&1, e=k&7):
//   element = W_p[k = t*64+s*32+lg*8+e][h = n*16+ln]
// A wave's B-fragment load becomes lane-linear: 64 lanes x 16B = 1KB contiguous.
// Grid 48 = 3p x 16 t-chunks.
// ---------------------------------------------------------------------------
__global__ void prep_w(const float* __restrict__ Wq, const float* __restrict__ Wk,
                       const float* __restrict__ Wv, unsigned short* __restrict__ WFrag) {
    __shared__ float tt[64][65];
    int p = blockIdx.x >> 4;
    int t = blockIdx.x & 15;
    int k0 = t * 64;
    const float* W = (p == 0) ? Wq : (p == 1) ? Wk : Wv;
    int tid = threadIdx.x;
#pragma unroll
    for (int j = 0; j < 16; j++) {
        int idx = tid + j * 256;
        int r = idx >> 6, c = idx & 63;
        tt[r][c] = W[(size_t)(k0 + r) * HD + c];      // coalesced read
    }
    __syncthreads();
#pragma unroll
    for (int gi = 0; gi < 2; gi++) {
        int g = tid * 2 + gi;                         // 512 groups
        int ln = g & 15, lg = (g >> 4) & 3, s = (g >> 6) & 1, n = (g >> 7) & 3;
        union { bf16x8 v; unsigned short u[8]; } pk;
#pragma unroll
        for (int e = 0; e < 8; e++)
            pk.u[e] = f2bf(tt[s * 32 + lg * 8 + e][n * 16 + ln]);
        *(bf16x8*)(WFrag + (((size_t)(p * 4 + n) * 16 + t) * 1024 + s * 512 + lg * 128 + ln * 8)) = pk.v;
    }
}

// ---------------------------------------------------------------------------
// Kernel 2: projections. BM=32, BN=192, K_STEP=64, grid 512 (2 blocks/CU).
// x: f32 -> regs (2-deep) -> cvt_pk -> swizzled LDS (4KB, dbuf).
// W: fragment-major global->reg, 1KB contiguous per load, 2 steps ahead.
// ---------------------------------------------------------------------------
__global__ __launch_bounds__(256) void proj_kernel(
    const float* __restrict__ x,
    const float* __restrict__ bq, const float* __restrict__ bk, const float* __restrict__ bv,
    const unsigned short* __restrict__ WFrag,
    unsigned short* __restrict__ Q, unsigned short* __restrict__ K,
    unsigned short* __restrict__ VT) {

    __shared__ __align__(16) unsigned short Xls[2][32 * 64];

    int tid = threadIdx.x;
    int w = tid >> 6, lane = tid & 63;
    int lg = lane >> 4, ln = lane & 15;
    int m0 = blockIdx.x * 32;

    // fragment-major W base pointers: wave's 3 frags, lane-linear
    const unsigned short* wbase[3];
#pragma unroll
    for (int j = 0; j < 3; j++)
        wbase[j] = WFrag + (size_t)(w * 3 + j) * 16384 + lane * 8;

    f32x4 acc[2][3];
#pragma unroll
    for (int m = 0; m < 2; m++)
#pragma unroll
        for (int j = 0; j < 3; j++) acc[m][j] = (f32x4){0.f, 0.f, 0.f, 0.f};

    f32x4 xq[2][2];
    bf16x8 bset[2][6];

    auto loadX = [&](int set, int k0) {
#pragma unroll
        for (int i = 0; i < 2; i++) {
            int c = tid + i * 256;
            xq[set][i] = *(const f32x4*)(x + (size_t)(m0 + (c >> 4)) * DMODEL + k0 + (c & 15) * 4);
        }
    };
    auto writeX = [&](unsigned short* buf, int set) {
#pragma unroll
        for (int i = 0; i < 2; i++) {
            int c = tid + i * 256;
            int row = c >> 4, slot = (c & 15) >> 1, half = c & 1;
            uint2v pk;
            pk[0] = cvtpk(xq[set][i][0], xq[set][i][1]);
            pk[1] = cvtpk(xq[set][i][2], xq[set][i][3]);
            *(uint2v*)((char*)buf + row * 128 + ((slot ^ (row & 7)) << 4) + half * 8) = pk;
        }
    };
    auto loadB = [&](int set, int k0) {
        int tb = (k0 >> 6) * 1024;
#pragma unroll
        for (int s = 0; s < 2; s++)
#pragma unroll
            for (int j = 0; j < 3; j++)
                bset[set][s * 3 + j] = *(const bf16x8*)(wbase[j] + tb + s * 512);
    };

    loadX(0, 0);
    writeX(&Xls[0][0], 0);
    loadX(1, 64);
    loadX(0, 128);
    loadB(0, 0);
    loadB(1, 64);
    __syncthreads();

#pragma unroll
    for (int t = 0; t < 16; t++) {
        const int cur = t & 1;
        const char* xb = (const char*)&Xls[cur][0];

#pragma unroll
        for (int s = 0; s < 2; s++) {
            bf16x8 a[2];
#pragma unroll
            for (int m = 0; m < 2; m++) {
                int row = m * 16 + ln;
                a[m] = *(const bf16x8*)(xb + row * 128 + (((s * 4 + lg) ^ (row & 7)) << 4));
            }
            __builtin_amdgcn_s_setprio(1);
#pragma unroll
            for (int m = 0; m < 2; m++)
#pragma unroll
                for (int j = 0; j < 3; j++)
                    acc[m][j] = __builtin_amdgcn_mfma_f32_16x16x32_bf16(a[m], bset[cur][s * 3 + j], acc[m][j], 0, 0, 0);
            __builtin_amdgcn_s_setprio(0);
        }

        if (t + 2 < 16) loadB(cur, (t + 2) * 64);
        if (t < 15) {
            writeX(&Xls[cur ^ 1][0], (t + 1) & 1);
            if (t + 3 < 16) loadX((t + 1) & 1, (t + 3) * 64);
        }
        __syncthreads();
    }

#pragma unroll
    for (int j = 0; j < 3; j++) {
        int f = w * 3 + j;
        int p = f >> 2, n = f & 3;
        int col = n * 16 + ln;
        const float* bias = (p == 0) ? bq : (p == 1) ? bk : bv;
        float bb = bias[col];
#pragma unroll
        for (int m = 0; m < 2; m++) {
#pragma unroll
            for (int r = 0; r < 4; r++) {
                float v = acc[m][j][r] + bb;
                int grow = m0 + m * 16 + lg * 4 + r;
                if (p == 0)      Q[(size_t)grow * HD + col] = f2bf(v);
                else if (p == 1) K[(size_t)grow * HD + col] = f2bf(v);
                else {
                    int b2 = grow >> 11, srow = grow & (SEQ - 1);
                    VT[((size_t)b2 * HD + col) * SEQ + srow] = f2bf(v);
                }
            }
        }
    }
}

// ---------------------------------------------------------------------------
// Kernel 3: flash attention, keys split 4x across blocks. 40KB LDS ->
// 4 blocks/CU. Mask loaded per-tile as int4 from global.
// Partials (bf16 O, f32 m/l) to workspace.  (unchanged from R7)
// ---------------------------------------------------------------------------
__device__ inline void stage_tile(int tid, const unsigned short* Kb, const unsigned short* VTb,
                                  int kt, unsigned short* kbuf, unsigned short* vbuf) {
#pragma unroll
    for (int i = 0; i < 2; i++) {
        int d = tid * 16 + i * 4096;
        int row = d >> 7, slot = (d >> 4) & 7;
        const unsigned short* src = Kb + (size_t)(kt + row) * HD + ((slot ^ (row & 7)) << 3);
        gl_lds16(src, (char*)kbuf + d);
    }
#pragma unroll
    for (int i = 0; i < 2; i++) {
        int d = tid * 16 + i * 4096;
        int row = d >> 7, slot = (d >> 4) & 7;
        const unsigned short* src = VTb + (size_t)row * SEQ + kt + ((slot ^ (row & 7)) << 3);
        gl_lds16(src, (char*)vbuf + d);
    }
}

__global__ __launch_bounds__(256, 4) void attn_kernel(
    const unsigned short* __restrict__ Q, const unsigned short* __restrict__ K,
    const unsigned short* __restrict__ VT, const int* __restrict__ mask,
    float* __restrict__ out,
    unsigned short* __restrict__ Op, float* __restrict__ Mp, float* __restrict__ Lp,
    int nsplit) {

    __shared__ __align__(16) unsigned short Kls[2][64 * 64];   // 16KB
    __shared__ __align__(16) unsigned short Vls[2][64 * 64];   // 16KB
    __shared__ __align__(16) unsigned short plds_[4][16 * 64]; // 8KB

    int tid = threadIdx.x;
    int w = tid >> 6, lane = tid & 63;
    int lg = lane >> 4, ln = lane & 15;
    int b = blockIdx.y;
    int kh = blockIdx.z;
    int q0 = blockIdx.x * 64 + w * 16;
    int ntiles = 32 / nsplit;
    int kt0 = kh * ntiles * 64;

    const float SC = 0.125f * 1.44269504088896f;

    const int* mb = mask + b * SEQ;

    bf16x8 qf[2];
    {
        const unsigned short* qptr = Q + ((size_t)b * SEQ + q0 + ln) * HD + lg * 8;
        qf[0] = *(const bf16x8*)(qptr);
        qf[1] = *(const bf16x8*)(qptr + 32);
    }

    f32x4 o[4];
#pragma unroll
    for (int n = 0; n < 4; n++) o[n] = (f32x4){0.f, 0.f, 0.f, 0.f};
    float mrun = -1e38f, lrun = 0.f;

    const unsigned short* Kb = K + (size_t)b * SEQ * HD;
    const unsigned short* VTb = VT + (size_t)b * HD * SEQ;

    unsigned short* kcur = &Kls[0][0]; unsigned short* knx = &Kls[1][0];
    unsigned short* vcur = &Vls[0][0]; unsigned short* vnx = &Vls[1][0];
    char* pl = (char*)&plds_[w][0];
    const int swz = (ln & 7) << 4;

    stage_tile(tid, Kb, VTb, kt0, kcur, vcur);
    __syncthreads();

#pragma unroll 2
    for (int tt = 0; tt < ntiles; ++tt) {
        int kt = kt0 + tt * 64;
        if (tt < ntiles - 1) stage_tile(tid, Kb, VTb, kt + 64, knx, vnx);

        int4v mi[4];
#pragma unroll
        for (int n = 0; n < 4; ++n)
            mi[n] = *(const int4v*)(mb + kt + n * 16 + lg * 4);

        f32x4 st[4];
        const char* kb = (const char*)kcur;
        __builtin_amdgcn_s_setprio(1);
#pragma unroll
        for (int n = 0; n < 4; ++n) {
            int rb = (n * 16 + ln) * 128;
            bf16x8 ka0 = *(const bf16x8*)(kb + ((rb + lg * 16) ^ swz));
            bf16x8 ka1 = *(const bf16x8*)(kb + ((rb + 64 + lg * 16) ^ swz));
            f32x4 z = (f32x4){0.f, 0.f, 0.f, 0.f};
            st[n] = __builtin_amdgcn_mfma_f32_16x16x32_bf16(ka0, qf[0], z, 0, 0, 0);
            st[n] = __builtin_amdgcn_mfma_f32_16x16x32_bf16(ka1, qf[1], st[n], 0, 0, 0);
        }
        __builtin_amdgcn_s_setprio(0);

#pragma unroll
        for (int n = 0; n < 4; ++n)
#pragma unroll
            for (int r = 0; r < 4; ++r)
                st[n][r] = fmaf(st[n][r], SC, mi[n][r] ? 0.f : -1e30f);

        f32x4 mx = st[0];
#pragma unroll
        for (int n = 1; n < 4; ++n)
#pragma unroll
            for (int r = 0; r < 4; ++r) mx[r] = fmaxf(mx[r], st[n][r]);
        float pmax = fmaxf(fmaxf(mx[0], mx[1]), fmaxf(mx[2], mx[3]));
        pmax = fmaxf(pmax, __shfl_xor(pmax, 16));
        pmax = fmaxf(pmax, __shfl_xor(pmax, 32));

        if (!__all(pmax <= mrun + 8.f)) {
            float mnew = fmaxf(mrun, pmax);
            float corr = exp2f(mrun - mnew);
            mrun = mnew;
            lrun *= corr;
            float c0 = __shfl(corr, lg * 4 + 0);
            float c1 = __shfl(corr, lg * 4 + 1);
            float c2 = __shfl(corr, lg * 4 + 2);
            float c3 = __shfl(corr, lg * 4 + 3);
#pragma unroll
            for (int n = 0; n < 4; ++n) {
                o[n][0] *= c0; o[n][1] *= c1; o[n][2] *= c2; o[n][3] *= c3;
            }
        }

        f32x4 sv = (f32x4){0.f, 0.f, 0.f, 0.f};
#pragma unroll
        for (int n = 0; n < 4; ++n)
#pragma unroll
            for (int r = 0; r < 4; ++r) {
                float pp = exp2f(st[n][r] - mrun);
                st[n][r] = pp;
                sv[r] += pp;
            }
        float ts = (sv[0] + sv[1]) + (sv[2] + sv[3]);
        ts += __shfl_xor(ts, 16);
        ts += __shfl_xor(ts, 32);
        lrun += ts;

#pragma unroll
        for (int n = 0; n < 4; ++n) {
            uint2v ww;
            ww[0] = cvtpk(st[n][0], st[n][1]);
            ww[1] = cvtpk(st[n][2], st[n][3]);
            *(uint2v*)(pl + ((ln * 128 + n * 32 + lg * 8) ^ swz)) = ww;
        }
        asm volatile("s_waitcnt lgkmcnt(0)" ::: "memory");
        __builtin_amdgcn_sched_barrier(0);
        bf16x8 pa0 = *(const bf16x8*)(pl + ((ln * 128 + lg * 16) ^ swz));
        bf16x8 pa1 = *(const bf16x8*)(pl + ((ln * 128 + 64 + lg * 16) ^ swz));

        const char* vb = (const char*)vcur;
        __builtin_amdgcn_s_setprio(1);
#pragma unroll
        for (int n = 0; n < 4; ++n) {
            int rb = (n * 16 + ln) * 128;
            bf16x8 v0 = *(const bf16x8*)(vb + ((rb + lg * 16) ^ swz));
            bf16x8 v1 = *(const bf16x8*)(vb + ((rb + 64 + lg * 16) ^ swz));
            o[n] = __builtin_amdgcn_mfma_f32_16x16x32_bf16(pa0, v0, o[n], 0, 0, 0);
            o[n] = __builtin_amdgcn_mfma_f32_16x16x32_bf16(pa1, v1, o[n], 0, 0, 0);
        }
        __builtin_amdgcn_s_setprio(0);

        __syncthreads();
        unsigned short* tk = kcur; kcur = knx; knx = tk;
        unsigned short* tv = vcur; vcur = vnx; vnx = tv;
    }

    if (nsplit == 1) {
#pragma unroll
        for (int r = 0; r < 4; r++) {
            float Lr = __shfl(lrun, lg * 4 + r);
            float inv = 1.0f / Lr;
            int row = q0 + lg * 4 + r;
#pragma unroll
            for (int n = 0; n < 4; n++)
                out[((size_t)b * SEQ + row) * HD + n * 16 + ln] = o[n][r] * inv;
        }
    } else {
        size_t base = (size_t)kh * BATCH * SEQ * HD;
#pragma unroll
        for (int r = 0; r < 4; r++) {
            int row = q0 + lg * 4 + r;
            size_t gr = (size_t)b * SEQ + row;
#pragma unroll
            for (int n = 0; n < 4; n++)
                Op[base + gr * HD + n * 16 + ln] = f2bf(o[n][r]);
        }
        if (lane < 16) {
            size_t gr = (size_t)b * SEQ + q0 + ln;
            Mp[(size_t)kh * BATCH * SEQ + gr] = mrun;
            Lp[(size_t)kh * BATCH * SEQ + gr] = lrun;
        }
    }
}

// ---------------------------------------------------------------------------
// Kernel 4: combine 4 key-split partials -> out. Thread = 8 cols of one row.
// ---------------------------------------------------------------------------
__global__ __launch_bounds__(256) void combine_kernel(
    const unsigned short* __restrict__ Op, const float* __restrict__ Mp,
    const float* __restrict__ Lp, float* __restrict__ out) {
    int g = blockIdx.x * 256 + threadIdx.x;
    int row = g >> 3;
    int c0 = (g & 7) * 8;
    const int NR = BATCH * SEQ;

    float m[4], l[4];
#pragma unroll
    for (int s = 0; s < 4; s++) {
        m[s] = Mp[(size_t)s * NR + row];
        l[s] = Lp[(size_t)s * NR + row];
    }
    float M = fmaxf(fmaxf(m[0], m[1]), fmaxf(m[2], m[3]));
    float e[4], L = 0.f;
#pragma unroll
    for (int s = 0; s < 4; s++) { e[s] = exp2f(m[s] - M); L += l[s] * e[s]; }
    float inv = 1.0f / L;

    float acc[8] = {0.f, 0.f, 0.f, 0.f, 0.f, 0.f, 0.f, 0.f};
#pragma unroll
    for (int s = 0; s < 4; s++) {
        bf16x8 ov = *(const bf16x8*)(Op + ((size_t)s * NR + row) * HD + c0);
#pragma unroll
        for (int i = 0; i < 8; i++) {
            float f = __builtin_bit_cast(float, ((u32)(unsigned short)ov[i]) << 16);
            acc[i] += f * e[s];
        }
    }
    f32x4 r0, r1;
#pragma unroll
    for (int i = 0; i < 4; i++) { r0[i] = acc[i] * inv; r1[i] = acc[4 + i] * inv; }
    *(f32x4*)(out + (size_t)row * HD + c0) = r0;
    *(f32x4*)(out + (size_t)row * HD + c0 + 4) = r1;
}

// ---------------------------------------------------------------------------
extern "C" void kernel_launch(void* const* d_in, const int* in_sizes, int n_in,
                              void* d_out, int out_size, void* d_ws, size_t ws_size,
                              hipStream_t stream) {
    const float* x  = (const float*)d_in[0];
    const int*   am = (const int*)d_in[1];
    const float* Wq = (const float*)d_in[2];
    const float* bq = (const float*)d_in[3];
    const float* Wk = (const float*)d_in[4];
    const float* bk = (const float*)d_in[5];
    const float* Wv = (const float*)d_in[6];
    const float* bv = (const float*)d_in[7];
    float* out = (float*)d_out;

    unsigned short* ws = (unsigned short*)d_ws;
    unsigned short* Wt  = ws;                               // WFrag, 196608 sh
    unsigned short* Qw  = ws + 3 * HD * DMODEL;
    unsigned short* Kw  = Qw + (size_t)BATCH * SEQ * HD;
    unsigned short* VTw = Kw + (size_t)BATCH * SEQ * HD;
    size_t base_sh = 3 * HD * DMODEL + 3 * (size_t)BATCH * SEQ * HD;
    unsigned short* Op = ws + base_sh;                      // [4][B*S][HD] bf16
    float* Mp = (float*)(Op + 4 * (size_t)BATCH * SEQ * HD);// [4][B*S]
    float* Lp = Mp + 4 * (size_t)BATCH * SEQ;               // [4][B*S]
    size_t need = base_sh * 2 + 4 * (size_t)BATCH * SEQ * HD * 2
                + 8 * (size_t)BATCH * SEQ * 4;

    int nsplit = (ws_size >= need) ? 4 : 1;

    prep_w<<<48, 256, 0, stream>>>(Wq, Wk, Wv, Wt);
    proj_kernel<<<(BATCH * SEQ) / 32, 256, 0, stream>>>(x, bq, bk, bv, Wt, Qw, Kw, VTw);
    attn_kernel<<<dim3(SEQ / 64, BATCH, nsplit), 256, 0, stream>>>(Qw, Kw, VTw, am, out,
                                                                   Op, Mp, Lp, nsplit);
    if (nsplit == 4)
        combine_kernel<<<(BATCH * SEQ * 8) / 256, 256, 0, stream>>>(Op, Mp, Lp, out);
}